// Round 1
// baseline (1285.077 us; speedup 1.0000x reference)
//
#include <hip/hip_runtime.h>
#include <math.h>

constexpr int N_ENT = 20000;
constexpr int N_REL = 500;
constexpr int NE    = 300000;   // entity triplets
constexpr int NER   = 50000;    // relation triplets
constexpr float EPSF = 1e-16f;

__device__ __forceinline__ float leaky(float x) { return x > 0.f ? x : 0.2f * x; }

// ---------------------------------------------------------------- GEMM
// C[M,N] = act( A[M,K] @ B^T (B is N x K, row stride ldb) + bias + add )
__global__ __launch_bounds__(256) void k_gemm(
    const float* __restrict__ A,
    const float* __restrict__ B, int ldb,
    const float* __restrict__ bias,
    const float* __restrict__ add,
    float* __restrict__ C,
    int M, int N, int K, int relu)
{
    __shared__ float As[32][65];
    __shared__ float Bs[32][65];
    int tid = threadIdx.x;
    int m0 = blockIdx.y * 64, n0 = blockIdx.x * 64;
    int tx = tid & 15, ty = tid >> 4;
    float acc[4][4] = {};
    for (int k0 = 0; k0 < K; k0 += 32) {
#pragma unroll
        for (int t = 0; t < 8; ++t) {
            int idx = t * 256 + tid;
            int m = idx >> 5, k = idx & 31;
            int gk = k0 + k;
            int gm = m0 + m;
            As[k][m] = (gm < M && gk < K) ? A[gm * K + gk] : 0.f;
            int gn = n0 + m;
            Bs[k][m] = (gn < N && gk < K) ? B[gn * ldb + gk] : 0.f;
        }
        __syncthreads();
#pragma unroll
        for (int k = 0; k < 32; ++k) {
            float a[4], b[4];
#pragma unroll
            for (int i = 0; i < 4; ++i) a[i] = As[k][ty * 4 + i];
#pragma unroll
            for (int j = 0; j < 4; ++j) b[j] = Bs[k][tx * 4 + j];
#pragma unroll
            for (int i = 0; i < 4; ++i)
#pragma unroll
                for (int j = 0; j < 4; ++j)
                    acc[i][j] = fmaf(a[i], b[j], acc[i][j]);
        }
        __syncthreads();
    }
#pragma unroll
    for (int i = 0; i < 4; ++i) {
        int gm = m0 + ty * 4 + i;
        if (gm >= M) continue;
#pragma unroll
        for (int j = 0; j < 4; ++j) {
            int gn = n0 + tx * 4 + j;
            if (gn >= N) continue;
            float v = acc[i][j];
            if (bias) v += bias[gn];
            if (add) v += add[gm * N + gn];
            if (relu) v = fmaxf(v, 0.f);
            C[gm * N + gn] = v;
        }
    }
}

// ---------------------------------------------------------------- CSR build
__global__ void k_count(const int* __restrict__ idx3, int off, int* cnt, int n) {
    int e = blockIdx.x * 256 + threadIdx.x;
    if (e < n) atomicAdd(&cnt[idx3[e * 3 + off]], 1);
}

__global__ void k_scan(const int* __restrict__ cnt, int* __restrict__ offs, int n) {
    __shared__ int sm[256];
    __shared__ int base;
    if (threadIdx.x == 0) base = 0;
    __syncthreads();
    for (int start = 0; start < n; start += 256) {
        int i = start + threadIdx.x;
        int v = (i < n) ? cnt[i] : 0;
        sm[threadIdx.x] = v;
        __syncthreads();
        for (int o = 1; o < 256; o <<= 1) {
            int addv = (threadIdx.x >= o) ? sm[threadIdx.x - o] : 0;
            __syncthreads();
            sm[threadIdx.x] += addv;
            __syncthreads();
        }
        int excl = sm[threadIdx.x] - v;
        if (i < n) offs[i] = base + excl;
        __syncthreads();
        if (threadIdx.x == 255) base += sm[255];
        __syncthreads();
    }
    if (threadIdx.x == 0) offs[n] = base;
}

__global__ void k_copy_int(const int* __restrict__ a, int* __restrict__ b, int n) {
    int i = blockIdx.x * 256 + threadIdx.x;
    if (i < n) b[i] = a[i];
}

__global__ void k_scatter(const int* __restrict__ idx3, int off, int* cur,
                          int* __restrict__ elist, int n) {
    int e = blockIdx.x * 256 + threadIdx.x;
    if (e >= n) return;
    int key = idx3[e * 3 + off];
    int pos = atomicAdd(&cur[key], 1);
    elist[pos] = e;
}

// ---------------------------------------------------------------- weight packing
// Bp1[384][128]: rows 0..127 Wa[:, :128]; 128..255 Wa[:,128:256]; 256..383 Wg[:, :128]
__global__ void k_pack_ent1(const float* __restrict__ Wa, const float* __restrict__ ba,
                            const float* __restrict__ Wg, const float* __restrict__ bg,
                            float* __restrict__ Bp, float* __restrict__ biasp) {
    int gid = blockIdx.x * 256 + threadIdx.x;
    if (gid < 384 * 128) {
        int row = gid >> 7, k = gid & 127;
        float v;
        if (row < 128) v = Wa[row * 320 + k];
        else if (row < 256) v = Wa[(row - 128) * 320 + 128 + k];
        else v = Wg[(row - 256) * 192 + k];
        Bp[gid] = v;
    }
    if (gid < 384)
        biasp[gid] = (gid < 128) ? ba[gid] : (gid < 256 ? 0.f : bg[gid - 256]);
}

// Bp2[256][64]: rows 0..127 Wa[:,256:320]; 128..255 Wg[:,128:192]
__global__ void k_pack_ent2(const float* __restrict__ Wa, const float* __restrict__ Wg,
                            float* __restrict__ Bp) {
    int gid = blockIdx.x * 256 + threadIdx.x;
    if (gid >= 256 * 64) return;
    int row = gid >> 6, k = gid & 63;
    Bp[gid] = (row < 128) ? Wa[row * 320 + 256 + k] : Wg[(row - 128) * 192 + 128 + k];
}

// Bp3[192][64]: rows 0..63 Wa[:, :64]; 64..127 Wa[:,64:128]; 128..191 Wg
__global__ void k_pack_rel(const float* __restrict__ Wa, const float* __restrict__ ba,
                           const float* __restrict__ Wg, const float* __restrict__ bg,
                           float* __restrict__ Bp, float* __restrict__ biasp) {
    int gid = blockIdx.x * 256 + threadIdx.x;
    if (gid < 192 * 64) {
        int row = gid >> 6, k = gid & 63;
        float v;
        if (row < 64) v = Wa[row * 128 + k];
        else if (row < 128) v = Wa[(row - 64) * 128 + 64 + k];
        else v = Wg[(row - 128) * 64 + k];
        Bp[gid] = v;
    }
    if (gid < 192)
        biasp[gid] = (gid < 64) ? ba[gid] : (gid < 128 ? 0.f : bg[gid - 128]);
}

// ---------------------------------------------------------------- rel layer
__global__ __launch_bounds__(256) void k_rel_raw(
    const float* __restrict__ Arel,   // 500x192: Ah+ba | At | Gg+bg
    const float* __restrict__ vec,    // 64
    const float* __restrict__ abin,   // 10x8
    const int* __restrict__ rt,
    float* __restrict__ raw)          // NER x 8
{
    int gid = blockIdx.x * 256 + threadIdx.x;
    int e = gid >> 6, col = gid & 63;
    if (e >= NER) return;
    int hi = rt[e * 3 + 0], ti = rt[e * 3 + 1], bin = rt[e * 3 + 2];
    float v = Arel[hi * 192 + col] + Arel[ti * 192 + 64 + col];
    v = leaky(v) * vec[col];
#pragma unroll
    for (int o = 1; o < 8; o <<= 1) v += __shfl_xor(v, o, 64);
    if ((col & 7) == 0) raw[e * 8 + (col >> 3)] = v + abin[bin * 8 + (col >> 3)];
}

__global__ __launch_bounds__(256) void k_rel_agg(
    const float* __restrict__ Arel, const float* __restrict__ raw,
    const int* __restrict__ rt, const int* __restrict__ offs,
    const int* __restrict__ elist, float* __restrict__ upd)
{
    int gid = blockIdx.x * 256 + threadIdx.x;
    int n = gid >> 6, col = gid & 63;
    if (n >= N_REL) return;
    int head = col >> 3;
    int e0 = offs[n], e1 = offs[n + 1];
    if (e0 == e1) { upd[n * 64 + col] = 0.f; return; }
    float m = -INFINITY;
    for (int i = e0; i < e1; ++i) m = fmaxf(m, raw[elist[i] * 8 + head]);
    float s = 0.f, acc = 0.f;
    for (int i = e0; i < e1; ++i) {
        int e = elist[i];
        float w = expf(raw[e * 8 + head] - m);
        s += w;
        int ti = rt[e * 3 + 1];
        acc += w * Arel[ti * 192 + 128 + col];
    }
    upd[n * 64 + col] = acc / (s + EPSF);
}

// ---------------------------------------------------------------- self_rel
__global__ __launch_bounds__(256) void k_self_rel(
    const float* __restrict__ xr, const int* __restrict__ tr,
    const int* __restrict__ offs, const int* __restrict__ elist,
    float* __restrict__ self_rel)
{
    int gid = blockIdx.x * 256 + threadIdx.x;
    int n = gid >> 6, col = gid & 63;
    if (n >= N_ENT) return;
    int e0 = offs[n], e1 = offs[n + 1];
    float acc = 0.f;
    for (int i = e0; i < e1; ++i) {
        int r = tr[elist[i] * 3 + 1];
        acc += xr[r * 64 + col];
    }
    self_rel[n * 64 + col] = acc / ((float)(e1 - e0) + EPSF);
}

// ---------------------------------------------------------------- ent layer
__global__ __launch_bounds__(256) void k_ent_raw(
    const float* __restrict__ P,    // 20000x384: Pt+ba | Ph | Gh+bg
    const float* __restrict__ S,    // 20000x256: RaS | GsS
    const float* __restrict__ Rr,   // 500x256:   Ra  | Gr
    const float* __restrict__ vec,  // 128
    const int* __restrict__ tr,
    float* __restrict__ raw)        // (NE+N_ENT) x 8
{
    int gid = blockIdx.x * 256 + threadIdx.x;
    int item = gid >> 7, col = gid & 127;
    if (item >= NE + N_ENT) return;
    float v;
    if (item < NE) {
        int h = tr[item * 3 + 0], r = tr[item * 3 + 1], t = tr[item * 3 + 2];
        v = P[t * 384 + col] + P[h * 384 + 128 + col] + Rr[r * 256 + col];
    } else {
        int n = item - NE;
        v = P[n * 384 + col] + P[n * 384 + 128 + col] + S[n * 256 + col];
    }
    v = leaky(v) * vec[col];
#pragma unroll
    for (int o = 1; o < 16; o <<= 1) v += __shfl_xor(v, o, 64);
    if ((col & 15) == 0) raw[item * 8 + (col >> 4)] = v;
}

__global__ __launch_bounds__(256) void k_ent_agg(
    const float* __restrict__ P, const float* __restrict__ S,
    const float* __restrict__ Rr, const float* __restrict__ raw,
    const int* __restrict__ tr, const int* __restrict__ offs,
    const int* __restrict__ elist, float* __restrict__ upd)
{
    int gid = blockIdx.x * 256 + threadIdx.x;
    int n = gid >> 7, col = gid & 127;
    if (n >= N_ENT) return;
    int head = col >> 4;
    int e0 = offs[n], e1 = offs[n + 1];
    float rs = raw[(NE + n) * 8 + head];
    float m = rs;
    for (int i = e0; i < e1; ++i) m = fmaxf(m, raw[elist[i] * 8 + head]);
    // self-loop term
    float a = expf(rs - m);
    float s = a;
    float acc = a * (P[n * 384 + 256 + col] + S[n * 256 + 128 + col]);
    for (int i = e0; i < e1; ++i) {
        int e = elist[i];
        float w = expf(raw[e * 8 + head] - m);
        s += w;
        int h = tr[e * 3 + 0], r = tr[e * 3 + 1];
        acc += w * (P[h * 384 + 256 + col] + Rr[r * 256 + 128 + col]);
    }
    upd[n * 128 + col] = acc / (s + EPSF);
}

// ---------------------------------------------------------------- launch
extern "C" void kernel_launch(void* const* d_in, const int* in_sizes, int n_in,
                              void* d_out, int out_size, void* d_ws, size_t ws_size,
                              hipStream_t stream) {
    const float* emb_ent      = (const float*)d_in[0];
    const float* emb_rel      = (const float*)d_in[1];
    const int*   tr           = (const int*)d_in[2];
    const int*   rt           = (const int*)d_in[3];
    const float* ent_proj1_W  = (const float*)d_in[4];
    const float* ent_proj1_b  = (const float*)d_in[5];
    const float* rel_proj1_W  = (const float*)d_in[6];
    const float* rel_proj1_b  = (const float*)d_in[7];
    const float* rel_attn_W   = (const float*)d_in[8];
    const float* rel_attn_b   = (const float*)d_in[9];
    const float* rel_attn_bin = (const float*)d_in[10];
    const float* rel_attn_vec = (const float*)d_in[11];
    const float* rel_aggr_W   = (const float*)d_in[12];
    const float* rel_aggr_b   = (const float*)d_in[13];
    const float* res_rel_W    = (const float*)d_in[14];
    const float* res_rel_b    = (const float*)d_in[15];
    const float* ent_attn_W   = (const float*)d_in[16];
    const float* ent_attn_b   = (const float*)d_in[17];
    const float* ent_attn_vec = (const float*)d_in[18];
    const float* ent_aggr_W   = (const float*)d_in[19];
    const float* ent_aggr_b   = (const float*)d_in[20];
    const float* res_ent_W    = (const float*)d_in[21];
    const float* res_ent_b    = (const float*)d_in[22];
    const float* ent_proj2_W  = (const float*)d_in[23];
    const float* ent_proj2_b  = (const float*)d_in[24];
    const float* rel_proj2_W  = (const float*)d_in[25];
    const float* rel_proj2_b  = (const float*)d_in[26];
    float* out = (float*)d_out;

    // workspace carve (256B aligned)
    size_t off = 0;
    char* base = (char*)d_ws;
    auto alloc = [&](size_t nbytes) -> void* {
        void* p = base + off;
        off += (nbytes + 255) & ~(size_t)255;
        return p;
    };
    float* xe0      = (float*)alloc((size_t)N_ENT * 128 * 4);
    float* xe1      = (float*)alloc((size_t)N_ENT * 128 * 4);
    float* xr0      = (float*)alloc((size_t)N_REL * 64 * 4);
    float* xr1      = (float*)alloc((size_t)N_REL * 64 * 4);
    float* self_rel = (float*)alloc((size_t)N_ENT * 64 * 4);
    float* P        = (float*)alloc((size_t)N_ENT * 384 * 4);
    float* S        = (float*)alloc((size_t)N_ENT * 256 * 4);
    float* Rrel     = (float*)alloc((size_t)N_REL * 256 * 4);
    float* Arel     = (float*)alloc((size_t)N_REL * 192 * 4);
    float* updE     = (float*)alloc((size_t)N_ENT * 128 * 4);
    float* updR     = (float*)alloc((size_t)N_REL * 64 * 4);
    float* rawE     = (float*)alloc((size_t)(NE + N_ENT) * 8 * 4);
    float* rawR     = (float*)alloc((size_t)NER * 8 * 4);
    float* Bp1      = (float*)alloc(384 * 128 * 4);
    float* bias1    = (float*)alloc(384 * 4);
    float* Bp2      = (float*)alloc(256 * 64 * 4);
    float* Bp3      = (float*)alloc(192 * 64 * 4);
    float* bias3    = (float*)alloc(192 * 4);
    int* cntE   = (int*)alloc(N_ENT * 4);
    int* offsE  = (int*)alloc((N_ENT + 1) * 4);
    int* curE   = (int*)alloc(N_ENT * 4);
    int* elistE = (int*)alloc((size_t)NE * 4);
    int* cntR   = (int*)alloc(N_REL * 4);
    int* offsR  = (int*)alloc((N_REL + 1) * 4);
    int* curR   = (int*)alloc(N_REL * 4);
    int* elistR = (int*)alloc((size_t)NER * 4);

    auto gemm = [&](const float* A, const float* B, int ldb, const float* bias,
                    const float* add, float* C, int M, int N, int K, int relu) {
        dim3 g((N + 63) / 64, (M + 63) / 64);
        k_gemm<<<g, 256, 0, stream>>>(A, B, ldb, bias, add, C, M, N, K, relu);
    };

    // ---- CSR over entity triplets (segment by tail t = col 2)
    hipMemsetAsync(cntE, 0, N_ENT * 4, stream);
    k_count<<<(NE + 255) / 256, 256, 0, stream>>>(tr, 2, cntE, NE);
    k_scan<<<1, 256, 0, stream>>>(cntE, offsE, N_ENT);
    k_copy_int<<<(N_ENT + 255) / 256, 256, 0, stream>>>(offsE, curE, N_ENT);
    k_scatter<<<(NE + 255) / 256, 256, 0, stream>>>(tr, 2, curE, elistE, NE);
    // ---- CSR over relation triplets (segment by hi = col 0)
    hipMemsetAsync(cntR, 0, N_REL * 4, stream);
    k_count<<<(NER + 255) / 256, 256, 0, stream>>>(rt, 0, cntR, NER);
    k_scan<<<1, 256, 0, stream>>>(cntR, offsR, N_REL);
    k_copy_int<<<(N_REL + 255) / 256, 256, 0, stream>>>(offsR, curR, N_REL);
    k_scatter<<<(NER + 255) / 256, 256, 0, stream>>>(rt, 0, curR, elistR, NER);

    // ---- input projections
    gemm(emb_ent, ent_proj1_W, 32, ent_proj1_b, nullptr, xe0, N_ENT, 128, 32, 0);
    gemm(emb_rel, rel_proj1_W, 16, rel_proj1_b, nullptr, xr0, N_REL, 64, 16, 0);

    // ---- relation layers
    for (int l = 0; l < 2; ++l) {
        const float* xin = l ? xr1 : xr0;
        float* xout = l ? xr0 : xr1;
        k_pack_rel<<<48, 256, 0, stream>>>(rel_attn_W + (size_t)l * 64 * 128,
                                           rel_attn_b + (size_t)l * 64,
                                           rel_aggr_W + (size_t)l * 64 * 64,
                                           rel_aggr_b + (size_t)l * 64, Bp3, bias3);
        gemm(xin, Bp3, 64, bias3, nullptr, Arel, N_REL, 192, 64, 0);
        k_rel_raw<<<(NER * 64) / 256, 256, 0, stream>>>(
            Arel, rel_attn_vec + (size_t)l * 64, rel_attn_bin + (size_t)l * 80, rt, rawR);
        k_rel_agg<<<(N_REL * 64) / 256, 256, 0, stream>>>(Arel, rawR, rt, offsR, elistR, updR);
        gemm(xin, res_rel_W + (size_t)l * 64 * 64, 64, res_rel_b + (size_t)l * 64,
             updR, xout, N_REL, 64, 64, 1);
    }

    // ---- self_rel (uses final x_rel = xr0; same for both ent layers)
    k_self_rel<<<(N_ENT * 64) / 256, 256, 0, stream>>>(xr0, tr, offsE, elistE, self_rel);

    // ---- entity layers
    for (int l = 0; l < 2; ++l) {
        const float* xin = l ? xe1 : xe0;
        float* xout = l ? xe0 : xe1;
        const float* Wa = ent_attn_W + (size_t)l * 128 * 320;
        const float* Wg = ent_aggr_W + (size_t)l * 128 * 192;
        k_pack_ent1<<<(384 * 128 + 255) / 256, 256, 0, stream>>>(
            Wa, ent_attn_b + (size_t)l * 128, Wg, ent_aggr_b + (size_t)l * 128, Bp1, bias1);
        k_pack_ent2<<<(256 * 64 + 255) / 256, 256, 0, stream>>>(Wa, Wg, Bp2);
        gemm(xin, Bp1, 128, bias1, nullptr, P, N_ENT, 384, 128, 0);
        gemm(self_rel, Bp2, 64, nullptr, nullptr, S, N_ENT, 256, 64, 0);
        gemm(xr0, Bp2, 64, nullptr, nullptr, Rrel, N_REL, 256, 64, 0);
        k_ent_raw<<<((NE + N_ENT) * 128) / 256, 256, 0, stream>>>(
            P, S, Rrel, ent_attn_vec + (size_t)l * 128, tr, rawE);
        k_ent_agg<<<(N_ENT * 128) / 256, 256, 0, stream>>>(
            P, S, Rrel, rawE, tr, offsE, elistE, updE);
        gemm(xin, res_ent_W + (size_t)l * 128 * 128, 128, res_ent_b + (size_t)l * 128,
             updE, xout, N_ENT, 128, 128, 1);
    }

    // ---- output projections
    gemm(xe0, ent_proj2_W, 128, ent_proj2_b, nullptr, out, N_ENT, 32, 128, 0);
    gemm(xr0, rel_proj2_W, 64, rel_proj2_b, nullptr, out + (size_t)N_ENT * 32,
         N_REL, 16, 64, 0);
}

// Round 2
// 637.823 us; speedup vs baseline: 2.0148x; 2.0148x over previous
//
#include <hip/hip_runtime.h>
#include <math.h>

constexpr int N_ENT = 20000;
constexpr int N_REL = 500;
constexpr int NE    = 300000;   // entity triplets
constexpr int NER   = 50000;    // relation triplets
constexpr float EPSF = 1e-16f;

__device__ __forceinline__ float leaky(float x) { return x > 0.f ? x : 0.2f * x; }

// ---------------------------------------------------------------- GEMM 64x64 (small problems)
__global__ __launch_bounds__(256) void k_gemm(
    const float* __restrict__ A,
    const float* __restrict__ B, int ldb,
    const float* __restrict__ bias,
    const float* __restrict__ add,
    float* __restrict__ C,
    int M, int N, int K, int relu)
{
    __shared__ float As[32][65];
    __shared__ float Bs[32][65];
    int tid = threadIdx.x;
    int m0 = blockIdx.y * 64, n0 = blockIdx.x * 64;
    int tx = tid & 15, ty = tid >> 4;
    float acc[4][4] = {};
    for (int k0 = 0; k0 < K; k0 += 32) {
#pragma unroll
        for (int t = 0; t < 8; ++t) {
            int idx = t * 256 + tid;
            int m = idx >> 5, k = idx & 31;
            int gk = k0 + k;
            int gm = m0 + m;
            As[k][m] = (gm < M && gk < K) ? A[(size_t)gm * K + gk] : 0.f;
            int gn = n0 + m;
            Bs[k][m] = (gn < N && gk < K) ? B[(size_t)gn * ldb + gk] : 0.f;
        }
        __syncthreads();
#pragma unroll
        for (int k = 0; k < 32; ++k) {
            float a[4], b[4];
#pragma unroll
            for (int i = 0; i < 4; ++i) a[i] = As[k][ty * 4 + i];
#pragma unroll
            for (int j = 0; j < 4; ++j) b[j] = Bs[k][tx * 4 + j];
#pragma unroll
            for (int i = 0; i < 4; ++i)
#pragma unroll
                for (int j = 0; j < 4; ++j)
                    acc[i][j] = fmaf(a[i], b[j], acc[i][j]);
        }
        __syncthreads();
    }
#pragma unroll
    for (int i = 0; i < 4; ++i) {
        int gm = m0 + ty * 4 + i;
        if (gm >= M) continue;
#pragma unroll
        for (int j = 0; j < 4; ++j) {
            int gn = n0 + tx * 4 + j;
            if (gn >= N) continue;
            float v = acc[i][j];
            if (bias) v += bias[gn];
            if (add) v += add[(size_t)gm * N + gn];
            if (relu) v = fmaxf(v, 0.f);
            C[(size_t)gm * N + gn] = v;
        }
    }
}

// ---------------------------------------------------------------- GEMM 128x128 (M=20000 problems)
// requires: K % 32 == 0, rows of A and B 16B-aligned, N % 4 == 0 (true: 128/256/384)
__global__ __launch_bounds__(256) void k_gemm128(
    const float* __restrict__ A,
    const float* __restrict__ B, int ldb,
    const float* __restrict__ bias,
    const float* __restrict__ add,
    float* __restrict__ C,
    int M, int N, int K, int relu)
{
    __shared__ float As[32][132];
    __shared__ float Bs[32][132];
    int tid = threadIdx.x;
    int m0 = blockIdx.y * 128, n0 = blockIdx.x * 128;
    int tx = tid & 15, ty = tid >> 4;
    float acc[8][8] = {};
    for (int k0 = 0; k0 < K; k0 += 32) {
#pragma unroll
        for (int t = 0; t < 4; ++t) {
            int idx = t * 256 + tid;      // 0..1023
            int m = idx >> 3;             // 0..127
            int k4 = idx & 7;             // 0..7 -> 4 k's each
            int gm = m0 + m;
            float4 av = make_float4(0.f, 0.f, 0.f, 0.f);
            if (gm < M) av = *(const float4*)&A[(size_t)gm * K + k0 + k4 * 4];
            As[k4 * 4 + 0][m] = av.x; As[k4 * 4 + 1][m] = av.y;
            As[k4 * 4 + 2][m] = av.z; As[k4 * 4 + 3][m] = av.w;
            int gn = n0 + m;
            float4 bv = make_float4(0.f, 0.f, 0.f, 0.f);
            if (gn < N) bv = *(const float4*)&B[(size_t)gn * ldb + k0 + k4 * 4];
            Bs[k4 * 4 + 0][m] = bv.x; Bs[k4 * 4 + 1][m] = bv.y;
            Bs[k4 * 4 + 2][m] = bv.z; Bs[k4 * 4 + 3][m] = bv.w;
        }
        __syncthreads();
#pragma unroll
        for (int k = 0; k < 32; ++k) {
            float a[8], b[8];
            *(float4*)&a[0] = *(const float4*)&As[k][ty * 8];
            *(float4*)&a[4] = *(const float4*)&As[k][ty * 8 + 4];
            *(float4*)&b[0] = *(const float4*)&Bs[k][tx * 8];
            *(float4*)&b[4] = *(const float4*)&Bs[k][tx * 8 + 4];
#pragma unroll
            for (int i = 0; i < 8; ++i)
#pragma unroll
                for (int j = 0; j < 8; ++j)
                    acc[i][j] = fmaf(a[i], b[j], acc[i][j]);
        }
        __syncthreads();
    }
#pragma unroll
    for (int i = 0; i < 8; ++i) {
        int gm = m0 + ty * 8 + i;
        if (gm >= M) continue;
#pragma unroll
        for (int jj = 0; jj < 2; ++jj) {
            int gn = n0 + tx * 8 + jj * 4;
            if (gn >= N) continue;
            float4 v;
            v.x = acc[i][jj * 4 + 0]; v.y = acc[i][jj * 4 + 1];
            v.z = acc[i][jj * 4 + 2]; v.w = acc[i][jj * 4 + 3];
            if (bias) {
                const float4 bb = *(const float4*)&bias[gn];
                v.x += bb.x; v.y += bb.y; v.z += bb.z; v.w += bb.w;
            }
            if (add) {
                const float4 aa = *(const float4*)&add[(size_t)gm * N + gn];
                v.x += aa.x; v.y += aa.y; v.z += aa.z; v.w += aa.w;
            }
            if (relu) {
                v.x = fmaxf(v.x, 0.f); v.y = fmaxf(v.y, 0.f);
                v.z = fmaxf(v.z, 0.f); v.w = fmaxf(v.w, 0.f);
            }
            *(float4*)&C[(size_t)gm * N + gn] = v;
        }
    }
}

// ---------------------------------------------------------------- CSR build (merged E+R)
__global__ void k_count2(const int* __restrict__ tr, const int* __restrict__ rt,
                         int* __restrict__ cntE, int* __restrict__ cntR) {
    int i = blockIdx.x * 256 + threadIdx.x;
    if (i < NE) atomicAdd(&cntE[tr[i * 3 + 2]], 1);
    else if (i < NE + NER) atomicAdd(&cntR[rt[(i - NE) * 3 + 0]], 1);
}

// single block, 1024 threads, shfl-based scan
__global__ __launch_bounds__(1024) void k_scan(const int* __restrict__ cnt,
                                               int* __restrict__ offs, int n) {
    __shared__ int wsum[16];
    __shared__ int sbase;
    int lane = threadIdx.x & 63, wid = threadIdx.x >> 6;
    if (threadIdx.x == 0) sbase = 0;
    __syncthreads();
    for (int start = 0; start < n; start += 1024) {
        int i = start + threadIdx.x;
        int v = (i < n) ? cnt[i] : 0;
        int x = v;
#pragma unroll
        for (int o = 1; o < 64; o <<= 1) {
            int y = __shfl_up(x, o, 64);
            if (lane >= o) x += y;
        }
        if (lane == 63) wsum[wid] = x;
        __syncthreads();
        if (wid == 0 && lane < 16) {
            int w = wsum[lane];
#pragma unroll
            for (int o = 1; o < 16; o <<= 1) {
                int y = __shfl_up(w, o, 64);
                if (lane >= o) w += y;
            }
            wsum[lane] = w;
        }
        __syncthreads();
        int excl = sbase + (wid ? wsum[wid - 1] : 0) + x - v;
        if (i < n) offs[i] = excl;
        __syncthreads();
        if (threadIdx.x == 0) sbase += wsum[15];
        __syncthreads();
    }
    if (threadIdx.x == 0) offs[n] = sbase;
}

__global__ void k_copy2(const int* __restrict__ offsE, const int* __restrict__ offsR,
                        int* __restrict__ curE, int* __restrict__ curR) {
    int i = blockIdx.x * 256 + threadIdx.x;
    if (i < N_ENT) curE[i] = offsE[i];
    else if (i < N_ENT + N_REL) curR[i - N_ENT] = offsR[i - N_ENT];
}

__global__ void k_scatter2(const int* __restrict__ tr, const int* __restrict__ rt,
                           int* __restrict__ curE, int* __restrict__ curR,
                           int* __restrict__ elistE, int* __restrict__ elistR) {
    int i = blockIdx.x * 256 + threadIdx.x;
    if (i < NE) {
        int pos = atomicAdd(&curE[tr[i * 3 + 2]], 1);
        elistE[pos] = i;
    } else if (i < NE + NER) {
        int e = i - NE;
        int pos = atomicAdd(&curR[rt[e * 3 + 0]], 1);
        elistR[pos] = e;
    }
}

// ---------------------------------------------------------------- weight packing
__global__ void k_pack_ent1(const float* __restrict__ Wa, const float* __restrict__ ba,
                            const float* __restrict__ Wg, const float* __restrict__ bg,
                            float* __restrict__ Bp, float* __restrict__ biasp) {
    int gid = blockIdx.x * 256 + threadIdx.x;
    if (gid < 384 * 128) {
        int row = gid >> 7, k = gid & 127;
        float v;
        if (row < 128) v = Wa[row * 320 + k];
        else if (row < 256) v = Wa[(row - 128) * 320 + 128 + k];
        else v = Wg[(row - 256) * 192 + k];
        Bp[gid] = v;
    }
    if (gid < 384)
        biasp[gid] = (gid < 128) ? ba[gid] : (gid < 256 ? 0.f : bg[gid - 256]);
}

__global__ void k_pack_ent2(const float* __restrict__ Wa, const float* __restrict__ Wg,
                            float* __restrict__ Bp) {
    int gid = blockIdx.x * 256 + threadIdx.x;
    if (gid >= 256 * 64) return;
    int row = gid >> 6, k = gid & 63;
    Bp[gid] = (row < 128) ? Wa[row * 320 + 256 + k] : Wg[(row - 128) * 192 + 128 + k];
}

__global__ void k_pack_rel(const float* __restrict__ Wa, const float* __restrict__ ba,
                           const float* __restrict__ Wg, const float* __restrict__ bg,
                           float* __restrict__ Bp, float* __restrict__ biasp) {
    int gid = blockIdx.x * 256 + threadIdx.x;
    if (gid < 192 * 64) {
        int row = gid >> 6, k = gid & 63;
        float v;
        if (row < 64) v = Wa[row * 128 + k];
        else if (row < 128) v = Wa[(row - 64) * 128 + 64 + k];
        else v = Wg[(row - 128) * 64 + k];
        Bp[gid] = v;
    }
    if (gid < 192)
        biasp[gid] = (gid < 64) ? ba[gid] : (gid < 128 ? 0.f : bg[gid - 128]);
}

// ---------------------------------------------------------------- rel layer (fused attn+agg, no-max softmax)
__global__ __launch_bounds__(256) void k_rel_fused(
    const float* __restrict__ Arel,   // 500x192: Ah+ba | At | Gg+bg
    const float* __restrict__ vec,    // 64
    const float* __restrict__ abin,   // 10x8
    const int* __restrict__ rt,
    const int* __restrict__ offs, const int* __restrict__ elist,
    float* __restrict__ upd)          // 500x64
{
    int gid = blockIdx.x * 256 + threadIdx.x;
    int n = gid >> 6, col = gid & 63;
    if (n >= N_REL) return;
    int head = col >> 3;
    float ah = Arel[n * 192 + col];
    float vc = vec[col];
    int e0 = offs[n], e1 = offs[n + 1];
    float s = 0.f, acc = 0.f;
    int i = e0;
    for (; i + 2 <= e1; i += 2) {
        int ea = elist[i], eb = elist[i + 1];
        int ta = rt[ea * 3 + 1], bina = rt[ea * 3 + 2];
        int tb = rt[eb * 3 + 1], binb = rt[eb * 3 + 2];
        float va = leaky(ah + Arel[ta * 192 + 64 + col]) * vc;
        float vb = leaky(ah + Arel[tb * 192 + 64 + col]) * vc;
        float ga = Arel[ta * 192 + 128 + col];
        float gb = Arel[tb * 192 + 128 + col];
#pragma unroll
        for (int o = 1; o < 8; o <<= 1) {
            va += __shfl_xor(va, o, 64);
            vb += __shfl_xor(vb, o, 64);
        }
        float wa = __expf(va + abin[bina * 8 + head]);
        float wb = __expf(vb + abin[binb * 8 + head]);
        s += wa + wb;
        acc = fmaf(wa, ga, fmaf(wb, gb, acc));
    }
    for (; i < e1; ++i) {
        int e = elist[i];
        int ti = rt[e * 3 + 1], bin = rt[e * 3 + 2];
        float v = leaky(ah + Arel[ti * 192 + 64 + col]) * vc;
        float g = Arel[ti * 192 + 128 + col];
#pragma unroll
        for (int o = 1; o < 8; o <<= 1) v += __shfl_xor(v, o, 64);
        float w = __expf(v + abin[bin * 8 + head]);
        s += w;
        acc = fmaf(w, g, acc);
    }
    upd[n * 64 + col] = acc / (s + EPSF);
}

// ---------------------------------------------------------------- self_rel
__global__ __launch_bounds__(256) void k_self_rel(
    const float* __restrict__ xr, const int* __restrict__ tr,
    const int* __restrict__ offs, const int* __restrict__ elist,
    float* __restrict__ self_rel)
{
    int gid = blockIdx.x * 256 + threadIdx.x;
    int n = gid >> 6, col = gid & 63;
    if (n >= N_ENT) return;
    int e0 = offs[n], e1 = offs[n + 1];
    float acc = 0.f;
    int i = e0;
    for (; i + 4 <= e1; i += 4) {
        int ea = elist[i], eb = elist[i + 1], ec = elist[i + 2], ed = elist[i + 3];
        int ra = tr[ea * 3 + 1], rb = tr[eb * 3 + 1];
        int rc = tr[ec * 3 + 1], rd = tr[ed * 3 + 1];
        acc += xr[ra * 64 + col] + xr[rb * 64 + col] + xr[rc * 64 + col] + xr[rd * 64 + col];
    }
    for (; i < e1; ++i) acc += xr[tr[elist[i] * 3 + 1] * 64 + col];
    self_rel[(size_t)n * 64 + col] = acc / ((float)(e1 - e0) + EPSF);
}

// ---------------------------------------------------------------- ent layer (fused attn+agg, no-max softmax)
__global__ __launch_bounds__(256) void k_ent_fused(
    const float* __restrict__ P,    // 20000x384: Pt+ba | Ph | Gh+bg
    const float* __restrict__ SR,   // (20000+? )x256: rows 0..19999 = S (self), rows 20000.. = rel
    const float* __restrict__ vec,  // 128
    const int* __restrict__ tr,
    const int* __restrict__ offs, const int* __restrict__ elist,
    float* __restrict__ upd)        // 20000x128
{
    int gid = blockIdx.x * 256 + threadIdx.x;
    int n = gid >> 7, col = gid & 127;
    const float* Rr = SR + (size_t)N_ENT * 256;
    float pt = P[(size_t)n * 384 + col];
    float vc = vec[col];
    // self-loop term
    float vs = leaky(pt + P[(size_t)n * 384 + 128 + col] + SR[(size_t)n * 256 + col]) * vc;
#pragma unroll
    for (int o = 1; o < 16; o <<= 1) vs += __shfl_xor(vs, o, 64);
    float ws = __expf(vs);
    float s = ws;
    float acc = ws * (P[(size_t)n * 384 + 256 + col] + SR[(size_t)n * 256 + 128 + col]);
    int e0 = offs[n], e1 = offs[n + 1];
    int i = e0;
    for (; i + 2 <= e1; i += 2) {
        int ea = elist[i], eb = elist[i + 1];
        int ha = tr[ea * 3], ra = tr[ea * 3 + 1];
        int hb = tr[eb * 3], rb = tr[eb * 3 + 1];
        const float* Pa = P + (size_t)ha * 384;
        const float* Pb = P + (size_t)hb * 384;
        const float* Ra = Rr + (size_t)ra * 256;
        const float* Rb = Rr + (size_t)rb * 256;
        float va = leaky(pt + Pa[128 + col] + Ra[col]) * vc;
        float vb = leaky(pt + Pb[128 + col] + Rb[col]) * vc;
        float ga = Pa[256 + col] + Ra[128 + col];
        float gb = Pb[256 + col] + Rb[128 + col];
#pragma unroll
        for (int o = 1; o < 16; o <<= 1) {
            va += __shfl_xor(va, o, 64);
            vb += __shfl_xor(vb, o, 64);
        }
        float wa = __expf(va), wb = __expf(vb);
        s += wa + wb;
        acc = fmaf(wa, ga, fmaf(wb, gb, acc));
    }
    for (; i < e1; ++i) {
        int e = elist[i];
        int h = tr[e * 3], r = tr[e * 3 + 1];
        const float* Ph = P + (size_t)h * 384;
        const float* Rh = Rr + (size_t)r * 256;
        float v = leaky(pt + Ph[128 + col] + Rh[col]) * vc;
#pragma unroll
        for (int o = 1; o < 16; o <<= 1) v += __shfl_xor(v, o, 64);
        float w = __expf(v);
        s += w;
        acc = fmaf(w, Ph[256 + col] + Rh[128 + col], acc);
    }
    upd[(size_t)n * 128 + col] = acc / (s + EPSF);
}

// ---------------------------------------------------------------- launch
extern "C" void kernel_launch(void* const* d_in, const int* in_sizes, int n_in,
                              void* d_out, int out_size, void* d_ws, size_t ws_size,
                              hipStream_t stream) {
    const float* emb_ent      = (const float*)d_in[0];
    const float* emb_rel      = (const float*)d_in[1];
    const int*   tr           = (const int*)d_in[2];
    const int*   rt           = (const int*)d_in[3];
    const float* ent_proj1_W  = (const float*)d_in[4];
    const float* ent_proj1_b  = (const float*)d_in[5];
    const float* rel_proj1_W  = (const float*)d_in[6];
    const float* rel_proj1_b  = (const float*)d_in[7];
    const float* rel_attn_W   = (const float*)d_in[8];
    const float* rel_attn_b   = (const float*)d_in[9];
    const float* rel_attn_bin = (const float*)d_in[10];
    const float* rel_attn_vec = (const float*)d_in[11];
    const float* rel_aggr_W   = (const float*)d_in[12];
    const float* rel_aggr_b   = (const float*)d_in[13];
    const float* res_rel_W    = (const float*)d_in[14];
    const float* res_rel_b    = (const float*)d_in[15];
    const float* ent_attn_W   = (const float*)d_in[16];
    const float* ent_attn_b   = (const float*)d_in[17];
    const float* ent_attn_vec = (const float*)d_in[18];
    const float* ent_aggr_W   = (const float*)d_in[19];
    const float* ent_aggr_b   = (const float*)d_in[20];
    const float* res_ent_W    = (const float*)d_in[21];
    const float* res_ent_b    = (const float*)d_in[22];
    const float* ent_proj2_W  = (const float*)d_in[23];
    const float* ent_proj2_b  = (const float*)d_in[24];
    const float* rel_proj2_W  = (const float*)d_in[25];
    const float* rel_proj2_b  = (const float*)d_in[26];
    float* out = (float*)d_out;

    // workspace carve (256B aligned)
    size_t off = 0;
    char* base = (char*)d_ws;
    auto alloc = [&](size_t nbytes) -> void* {
        void* p = base + off;
        off += (nbytes + 255) & ~(size_t)255;
        return p;
    };
    float* xe0    = (float*)alloc((size_t)N_ENT * 128 * 4);
    float* xe1    = (float*)alloc((size_t)N_ENT * 128 * 4);
    float* xr0    = (float*)alloc((size_t)N_REL * 64 * 4);
    float* xr1    = (float*)alloc((size_t)N_REL * 64 * 4);
    float* SRsrc  = (float*)alloc((size_t)(N_ENT + N_REL) * 64 * 4);  // self_rel rows then xr rows
    float* P      = (float*)alloc((size_t)N_ENT * 384 * 4);
    float* SR     = (float*)alloc((size_t)(N_ENT + N_REL) * 256 * 4); // S rows then Rr rows
    float* Arel   = (float*)alloc((size_t)N_REL * 192 * 4);
    float* updE   = (float*)alloc((size_t)N_ENT * 128 * 4);
    float* updR   = (float*)alloc((size_t)N_REL * 64 * 4);
    float* Bp1    = (float*)alloc(384 * 128 * 4);
    float* bias1  = (float*)alloc(384 * 4);
    float* Bp2    = (float*)alloc(256 * 64 * 4);
    float* Bp3    = (float*)alloc(192 * 64 * 4);
    float* bias3  = (float*)alloc(192 * 4);
    int* cnt    = (int*)alloc((size_t)(N_ENT + N_REL) * 4);  // cntE | cntR contiguous
    int* cntE   = cnt;
    int* cntR   = cnt + N_ENT;
    int* offsE  = (int*)alloc((N_ENT + 1) * 4);
    int* offsR  = (int*)alloc((N_REL + 1) * 4);
    int* curE   = (int*)alloc(N_ENT * 4);
    int* curR   = (int*)alloc(N_REL * 4);
    int* elistE = (int*)alloc((size_t)NE * 4);
    int* elistR = (int*)alloc((size_t)NER * 4);

    auto gemm64 = [&](const float* A, const float* B, int ldb, const float* bias,
                      const float* add, float* C, int M, int N, int K, int relu) {
        dim3 g((N + 63) / 64, (M + 63) / 64);
        k_gemm<<<g, 256, 0, stream>>>(A, B, ldb, bias, add, C, M, N, K, relu);
    };
    auto gemm128 = [&](const float* A, const float* B, int ldb, const float* bias,
                       const float* add, float* C, int M, int N, int K, int relu) {
        dim3 g((N + 127) / 128, (M + 127) / 128);
        k_gemm128<<<g, 256, 0, stream>>>(A, B, ldb, bias, add, C, M, N, K, relu);
    };

    // ---- CSR builds (E by tail, R by head) — merged launches
    hipMemsetAsync(cnt, 0, (size_t)(N_ENT + N_REL) * 4, stream);
    k_count2<<<(NE + NER + 255) / 256, 256, 0, stream>>>(tr, rt, cntE, cntR);
    k_scan<<<1, 1024, 0, stream>>>(cntE, offsE, N_ENT);
    k_scan<<<1, 1024, 0, stream>>>(cntR, offsR, N_REL);
    k_copy2<<<(N_ENT + N_REL + 255) / 256, 256, 0, stream>>>(offsE, offsR, curE, curR);
    k_scatter2<<<(NE + NER + 255) / 256, 256, 0, stream>>>(tr, rt, curE, curR, elistE, elistR);

    // ---- input projections
    gemm128(emb_ent, ent_proj1_W, 32, ent_proj1_b, nullptr, xe0, N_ENT, 128, 32, 0);
    gemm64(emb_rel, rel_proj1_W, 16, rel_proj1_b, nullptr, xr0, N_REL, 64, 16, 0);

    // ---- relation layers
    for (int l = 0; l < 2; ++l) {
        const float* xin = l ? xr1 : xr0;
        float* xout = l ? xr0 : xr1;
        k_pack_rel<<<48, 256, 0, stream>>>(rel_attn_W + (size_t)l * 64 * 128,
                                           rel_attn_b + (size_t)l * 64,
                                           rel_aggr_W + (size_t)l * 64 * 64,
                                           rel_aggr_b + (size_t)l * 64, Bp3, bias3);
        gemm64(xin, Bp3, 64, bias3, nullptr, Arel, N_REL, 192, 64, 0);
        k_rel_fused<<<(N_REL * 64) / 256, 256, 0, stream>>>(
            Arel, rel_attn_vec + (size_t)l * 64, rel_attn_bin + (size_t)l * 80,
            rt, offsR, elistR, updR);
        gemm64(xin, res_rel_W + (size_t)l * 64 * 64, 64, res_rel_b + (size_t)l * 64,
               updR, xout, N_REL, 64, 64, 1);
    }
    // final x_rel = xr0

    // ---- self_rel into SRsrc rows 0..N_ENT-1; xr rows appended
    k_self_rel<<<(N_ENT * 64) / 256, 256, 0, stream>>>(xr0, tr, offsE, elistE, SRsrc);
    hipMemcpyAsync(SRsrc + (size_t)N_ENT * 64, xr0, (size_t)N_REL * 64 * 4,
                   hipMemcpyDeviceToDevice, stream);

    // ---- entity layers
    for (int l = 0; l < 2; ++l) {
        const float* xin = l ? xe1 : xe0;
        float* xout = l ? xe0 : xe1;
        const float* Wa = ent_attn_W + (size_t)l * 128 * 320;
        const float* Wg = ent_aggr_W + (size_t)l * 128 * 192;
        k_pack_ent1<<<(384 * 128 + 255) / 256, 256, 0, stream>>>(
            Wa, ent_attn_b + (size_t)l * 128, Wg, ent_aggr_b + (size_t)l * 128, Bp1, bias1);
        k_pack_ent2<<<(256 * 64 + 255) / 256, 256, 0, stream>>>(Wa, Wg, Bp2);
        gemm128(xin, Bp1, 128, bias1, nullptr, P, N_ENT, 384, 128, 0);
        gemm128(SRsrc, Bp2, 64, nullptr, nullptr, SR, N_ENT + N_REL, 256, 64, 0);
        k_ent_fused<<<(N_ENT * 128) / 256, 256, 0, stream>>>(
            P, SR, ent_attn_vec + (size_t)l * 128, tr, offsE, elistE, updE);
        gemm128(xin, res_ent_W + (size_t)l * 128 * 128, 128, res_ent_b + (size_t)l * 128,
                updE, xout, N_ENT, 128, 128, 1);
    }
    // final x_ent = xe0

    // ---- output projections
    gemm64(xe0, ent_proj2_W, 128, ent_proj2_b, nullptr, out, N_ENT, 32, 128, 0);
    gemm64(xr0, rel_proj2_W, 64, rel_proj2_b, nullptr, out + (size_t)N_ENT * 32,
           N_REL, 16, 64, 0);
}

// Round 3
// 493.189 us; speedup vs baseline: 2.6056x; 1.2933x over previous
//
#include <hip/hip_runtime.h>
#include <hip/hip_fp16.h>
#include <math.h>

constexpr int N_ENT = 20000;
constexpr int N_REL = 500;
constexpr int NE    = 300000;   // entity triplets
constexpr int NER   = 50000;    // relation triplets
constexpr float EPSF = 1e-16f;

__device__ __forceinline__ float leaky(float x) { return x > 0.f ? x : 0.2f * x; }

// ---------------------------------------------------------------- GEMM 64x64 (small problems, fp32)
__global__ __launch_bounds__(256) void k_gemm(
    const float* __restrict__ A,
    const float* __restrict__ B, int ldb,
    const float* __restrict__ bias,
    const float* __restrict__ add,
    float* __restrict__ C,
    int M, int N, int K, int relu)
{
    __shared__ float As[32][65];
    __shared__ float Bs[32][65];
    int tid = threadIdx.x;
    int m0 = blockIdx.y * 64, n0 = blockIdx.x * 64;
    int tx = tid & 15, ty = tid >> 4;
    float acc[4][4] = {};
    for (int k0 = 0; k0 < K; k0 += 32) {
#pragma unroll
        for (int t = 0; t < 8; ++t) {
            int idx = t * 256 + tid;
            int m = idx >> 5, k = idx & 31;
            int gk = k0 + k;
            int gm = m0 + m;
            As[k][m] = (gm < M && gk < K) ? A[(size_t)gm * K + gk] : 0.f;
            int gn = n0 + m;
            Bs[k][m] = (gn < N && gk < K) ? B[(size_t)gn * ldb + gk] : 0.f;
        }
        __syncthreads();
#pragma unroll
        for (int k = 0; k < 32; ++k) {
            float a[4], b[4];
#pragma unroll
            for (int i = 0; i < 4; ++i) a[i] = As[k][ty * 4 + i];
#pragma unroll
            for (int j = 0; j < 4; ++j) b[j] = Bs[k][tx * 4 + j];
#pragma unroll
            for (int i = 0; i < 4; ++i)
#pragma unroll
                for (int j = 0; j < 4; ++j)
                    acc[i][j] = fmaf(a[i], b[j], acc[i][j]);
        }
        __syncthreads();
    }
#pragma unroll
    for (int i = 0; i < 4; ++i) {
        int gm = m0 + ty * 4 + i;
        if (gm >= M) continue;
#pragma unroll
        for (int j = 0; j < 4; ++j) {
            int gn = n0 + tx * 4 + j;
            if (gn >= N) continue;
            float v = acc[i][j];
            if (bias) v += bias[gn];
            if (add) v += add[(size_t)gm * N + gn];
            if (relu) v = fmaxf(v, 0.f);
            C[(size_t)gm * N + gn] = v;
        }
    }
}

// ---------------------------------------------------------------- GEMM 128x128, mixed-dtype epilogue
// mode 0: column-split at `split` -> C32 (ld=split) fp32 | C16 (ld=N-split) fp16
// mode 1: row-split    at `split` -> C32 (ld=N)  fp32 rows < split | C16 (ld=N) fp16 rows >= split
// mode 2: plain fp32 with optional add/relu
// requires: K % 32 == 0, rows of A/B 16B-aligned, N % 4 == 0, split % 4 == 0 for mode 0
__global__ __launch_bounds__(256) void k_gemm128x(
    const float* __restrict__ A,
    const float* __restrict__ B, int ldb,
    const float* __restrict__ bias,
    const float* __restrict__ add,
    float* __restrict__ C32, __half* __restrict__ C16,
    int split, int mode,
    int M, int N, int K, int relu)
{
    __shared__ float As[32][132];
    __shared__ float Bs[32][132];
    int tid = threadIdx.x;
    int m0 = blockIdx.y * 128, n0 = blockIdx.x * 128;
    int tx = tid & 15, ty = tid >> 4;
    float acc[8][8] = {};
    for (int k0 = 0; k0 < K; k0 += 32) {
#pragma unroll
        for (int t = 0; t < 4; ++t) {
            int idx = t * 256 + tid;      // 0..1023
            int m = idx >> 3;             // 0..127
            int k4 = idx & 7;             // 0..7 -> 4 k's each
            int gm = m0 + m;
            float4 av = make_float4(0.f, 0.f, 0.f, 0.f);
            if (gm < M) av = *(const float4*)&A[(size_t)gm * K + k0 + k4 * 4];
            As[k4 * 4 + 0][m] = av.x; As[k4 * 4 + 1][m] = av.y;
            As[k4 * 4 + 2][m] = av.z; As[k4 * 4 + 3][m] = av.w;
            int gn = n0 + m;
            float4 bv = make_float4(0.f, 0.f, 0.f, 0.f);
            if (gn < N) bv = *(const float4*)&B[(size_t)gn * ldb + k0 + k4 * 4];
            Bs[k4 * 4 + 0][m] = bv.x; Bs[k4 * 4 + 1][m] = bv.y;
            Bs[k4 * 4 + 2][m] = bv.z; Bs[k4 * 4 + 3][m] = bv.w;
        }
        __syncthreads();
#pragma unroll
        for (int k = 0; k < 32; ++k) {
            float a[8], b[8];
            *(float4*)&a[0] = *(const float4*)&As[k][ty * 8];
            *(float4*)&a[4] = *(const float4*)&As[k][ty * 8 + 4];
            *(float4*)&b[0] = *(const float4*)&Bs[k][tx * 8];
            *(float4*)&b[4] = *(const float4*)&Bs[k][tx * 8 + 4];
#pragma unroll
            for (int i = 0; i < 8; ++i)
#pragma unroll
                for (int j = 0; j < 8; ++j)
                    acc[i][j] = fmaf(a[i], b[j], acc[i][j]);
        }
        __syncthreads();
    }
#pragma unroll
    for (int i = 0; i < 8; ++i) {
        int gm = m0 + ty * 8 + i;
        if (gm >= M) continue;
#pragma unroll
        for (int jj = 0; jj < 2; ++jj) {
            int gn = n0 + tx * 8 + jj * 4;
            if (gn >= N) continue;
            float4 v;
            v.x = acc[i][jj * 4 + 0]; v.y = acc[i][jj * 4 + 1];
            v.z = acc[i][jj * 4 + 2]; v.w = acc[i][jj * 4 + 3];
            if (bias) {
                const float4 bb = *(const float4*)&bias[gn];
                v.x += bb.x; v.y += bb.y; v.z += bb.z; v.w += bb.w;
            }
            if (mode == 2) {
                if (add) {
                    const float4 aa = *(const float4*)&add[(size_t)gm * N + gn];
                    v.x += aa.x; v.y += aa.y; v.z += aa.z; v.w += aa.w;
                }
                if (relu) {
                    v.x = fmaxf(v.x, 0.f); v.y = fmaxf(v.y, 0.f);
                    v.z = fmaxf(v.z, 0.f); v.w = fmaxf(v.w, 0.f);
                }
                *(float4*)&C32[(size_t)gm * N + gn] = v;
            } else if (mode == 0) {
                if (gn < split) {
                    *(float4*)&C32[(size_t)gm * split + gn] = v;
                } else {
                    __half* dst = C16 + (size_t)gm * (N - split) + (gn - split);
                    *(__half2*)dst       = __floats2half2_rn(v.x, v.y);
                    *(__half2*)(dst + 2) = __floats2half2_rn(v.z, v.w);
                }
            } else { // mode 1
                if (gm < split) {
                    *(float4*)&C32[(size_t)gm * N + gn] = v;
                } else {
                    __half* dst = C16 + (size_t)(gm - split) * N + gn;
                    *(__half2*)dst       = __floats2half2_rn(v.x, v.y);
                    *(__half2*)(dst + 2) = __floats2half2_rn(v.z, v.w);
                }
            }
        }
    }
}

// ---------------------------------------------------------------- mega-pack (all layers) + zero counters
__global__ void k_pack_all(
    const float* __restrict__ Wa_e, const float* __restrict__ ba_e,
    const float* __restrict__ Wg_e, const float* __restrict__ bg_e,
    const float* __restrict__ Wa_r, const float* __restrict__ ba_r,
    const float* __restrict__ Wg_r, const float* __restrict__ bg_r,
    float* __restrict__ Bp1, float* __restrict__ bias1,
    float* __restrict__ Bp2,
    float* __restrict__ Bp3, float* __restrict__ bias3,
    int* __restrict__ cnt)
{
    int gid = blockIdx.x * 256 + threadIdx.x;
    if (gid < 2 * 384 * 128) {          // Bp1[l][384][128]
        int l = gid / (384 * 128), rem = gid % (384 * 128);
        int row = rem >> 7, k = rem & 127;
        const float* Wa = Wa_e + (size_t)l * 128 * 320;
        const float* Wg = Wg_e + (size_t)l * 128 * 192;
        float v;
        if (row < 128) v = Wa[row * 320 + k];
        else if (row < 256) v = Wa[(row - 128) * 320 + 128 + k];
        else v = Wg[(row - 256) * 192 + k];
        Bp1[gid] = v;
    }
    if (gid < 512 * 64) {               // Bp2[l*256 + (att|agg)][64]
        int row = gid >> 6, k = gid & 63;
        int l = row >> 8, r2 = row & 255;
        const float* Wa = Wa_e + (size_t)l * 128 * 320;
        const float* Wg = Wg_e + (size_t)l * 128 * 192;
        Bp2[gid] = (r2 < 128) ? Wa[r2 * 320 + 256 + k] : Wg[(r2 - 128) * 192 + 128 + k];
    }
    if (gid < 2 * 192 * 64) {           // Bp3[l][192][64]
        int l = gid / (192 * 64), rem = gid % (192 * 64);
        int row = rem >> 6, k = rem & 63;
        const float* Wa = Wa_r + (size_t)l * 64 * 128;
        const float* Wg = Wg_r + (size_t)l * 64 * 64;
        float v;
        if (row < 64) v = Wa[row * 128 + k];
        else if (row < 128) v = Wa[(row - 64) * 128 + 64 + k];
        else v = Wg[(row - 128) * 64 + k];
        Bp3[gid] = v;
    }
    if (gid < 2 * 384) {
        int l = gid / 384, j = gid % 384;
        bias1[gid] = (j < 128) ? ba_e[l * 128 + j] : (j < 256 ? 0.f : bg_e[l * 128 + j - 256]);
    }
    if (gid < 2 * 192) {
        int l = gid / 192, j = gid % 192;
        bias3[gid] = (j < 64) ? ba_r[l * 64 + j] : (j < 128 ? 0.f : bg_r[l * 64 + j - 128]);
    }
    if (gid < N_ENT + N_REL) cnt[gid] = 0;
}

// ---------------------------------------------------------------- CSR build
__global__ void k_count2(const int* __restrict__ tr, const int* __restrict__ rt,
                         int* __restrict__ cntE, int* __restrict__ cntR) {
    int i = blockIdx.x * 256 + threadIdx.x;
    if (i < NE) atomicAdd(&cntE[tr[i * 3 + 2]], 1);
    else if (i < NE + NER) atomicAdd(&cntR[rt[(i - NE) * 3 + 0]], 1);
}

// grid 2: block 0 scans cntE->offsE/curE; block 1 scans cntR->offsR/curR
__global__ __launch_bounds__(1024) void k_scan2(
    const int* __restrict__ cntE, int* __restrict__ offsE, int* __restrict__ curE,
    const int* __restrict__ cntR, int* __restrict__ offsR, int* __restrict__ curR)
{
    const int* cnt = blockIdx.x ? cntR : cntE;
    int* offs = blockIdx.x ? offsR : offsE;
    int* cur  = blockIdx.x ? curR : curE;
    int n = blockIdx.x ? N_REL : N_ENT;
    __shared__ int wsum[16];
    __shared__ int sbase;
    int lane = threadIdx.x & 63, wid = threadIdx.x >> 6;
    if (threadIdx.x == 0) sbase = 0;
    __syncthreads();
    for (int start = 0; start < n; start += 1024) {
        int i = start + threadIdx.x;
        int v = (i < n) ? cnt[i] : 0;
        int x = v;
#pragma unroll
        for (int o = 1; o < 64; o <<= 1) {
            int y = __shfl_up(x, o, 64);
            if (lane >= o) x += y;
        }
        if (lane == 63) wsum[wid] = x;
        __syncthreads();
        if (wid == 0 && lane < 16) {
            int w = wsum[lane];
#pragma unroll
            for (int o = 1; o < 16; o <<= 1) {
                int y = __shfl_up(w, o, 64);
                if (lane >= o) w += y;
            }
            wsum[lane] = w;
        }
        __syncthreads();
        int excl = sbase + (wid ? wsum[wid - 1] : 0) + x - v;
        if (i < n) { offs[i] = excl; cur[i] = excl; }
        __syncthreads();
        if (threadIdx.x == 0) sbase += wsum[15];
        __syncthreads();
    }
    if (threadIdx.x == 0) offs[n] = sbase;
}

// scatter edge payloads directly (kills the tr/rt gather in the hot kernels)
__global__ void k_scatter2(const int* __restrict__ tr, const int* __restrict__ rt,
                           int* __restrict__ curE, int* __restrict__ curR,
                           int2* __restrict__ hrE, int2* __restrict__ tbR) {
    int i = blockIdx.x * 256 + threadIdx.x;
    if (i < NE) {
        int pos = atomicAdd(&curE[tr[i * 3 + 2]], 1);
        hrE[pos] = make_int2(tr[i * 3 + 0], tr[i * 3 + 1]);
    } else if (i < NE + NER) {
        int e = i - NE;
        int pos = atomicAdd(&curR[rt[e * 3 + 0]], 1);
        tbR[pos] = make_int2(rt[e * 3 + 1], rt[e * 3 + 2]);
    }
}

// ---------------------------------------------------------------- rel layer (fused, no-max softmax)
__global__ __launch_bounds__(256) void k_rel_fused(
    const float* __restrict__ Arel,   // 500x192: Ah+ba | At | G+bg
    const float* __restrict__ vec,    // 64
    const float* __restrict__ abin,   // 10x8
    const int2* __restrict__ tbR,
    const int* __restrict__ offs,
    float* __restrict__ upd)          // 500x64
{
    int gid = blockIdx.x * 256 + threadIdx.x;
    int n = gid >> 6, col = gid & 63;
    int head = col >> 3;
    float ah = Arel[n * 192 + col];
    float vc = vec[col];
    int e0 = offs[n], e1 = offs[n + 1];
    float s = 0.f, acc = 0.f;
    int i = e0;
    for (; i + 4 <= e1; i += 4) {
        int2 t0 = tbR[i], t1 = tbR[i + 1], t2 = tbR[i + 2], t3 = tbR[i + 3];
        float v0 = leaky(ah + Arel[t0.x * 192 + 64 + col]) * vc;
        float v1 = leaky(ah + Arel[t1.x * 192 + 64 + col]) * vc;
        float v2 = leaky(ah + Arel[t2.x * 192 + 64 + col]) * vc;
        float v3 = leaky(ah + Arel[t3.x * 192 + 64 + col]) * vc;
        float g0 = Arel[t0.x * 192 + 128 + col];
        float g1 = Arel[t1.x * 192 + 128 + col];
        float g2 = Arel[t2.x * 192 + 128 + col];
        float g3 = Arel[t3.x * 192 + 128 + col];
#pragma unroll
        for (int o = 1; o < 8; o <<= 1) {
            v0 += __shfl_xor(v0, o, 64); v1 += __shfl_xor(v1, o, 64);
            v2 += __shfl_xor(v2, o, 64); v3 += __shfl_xor(v3, o, 64);
        }
        float w0 = __expf(v0 + abin[t0.y * 8 + head]);
        float w1 = __expf(v1 + abin[t1.y * 8 + head]);
        float w2 = __expf(v2 + abin[t2.y * 8 + head]);
        float w3 = __expf(v3 + abin[t3.y * 8 + head]);
        s += (w0 + w1) + (w2 + w3);
        acc = fmaf(w0, g0, acc); acc = fmaf(w1, g1, acc);
        acc = fmaf(w2, g2, acc); acc = fmaf(w3, g3, acc);
    }
    for (; i < e1; ++i) {
        int2 tb = tbR[i];
        float v = leaky(ah + Arel[tb.x * 192 + 64 + col]) * vc;
        float g = Arel[tb.x * 192 + 128 + col];
#pragma unroll
        for (int o = 1; o < 8; o <<= 1) v += __shfl_xor(v, o, 64);
        float w = __expf(v + abin[tb.y * 8 + head]);
        s += w;
        acc = fmaf(w, g, acc);
    }
    upd[n * 64 + col] = acc / (s + EPSF);
}

// ---------------------------------------------------------------- self_rel (+ append xr rows into SRsrc)
__global__ __launch_bounds__(256) void k_self_rel(
    const float* __restrict__ xr, const int2* __restrict__ hrE,
    const int* __restrict__ offs, float* __restrict__ SRsrc)
{
    int gid = blockIdx.x * 256 + threadIdx.x;
    if (gid < N_ENT * 64) {
        int n = gid >> 6, col = gid & 63;
        int e0 = offs[n], e1 = offs[n + 1];
        float acc = 0.f;
        int i = e0;
        for (; i + 4 <= e1; i += 4) {
            int r0 = hrE[i].y, r1 = hrE[i + 1].y, r2 = hrE[i + 2].y, r3 = hrE[i + 3].y;
            acc += xr[r0 * 64 + col] + xr[r1 * 64 + col] + xr[r2 * 64 + col] + xr[r3 * 64 + col];
        }
        for (; i < e1; ++i) acc += xr[hrE[i].y * 64 + col];
        SRsrc[(size_t)n * 64 + col] = acc / ((float)(e1 - e0) + EPSF);
    } else {
        int j = gid - N_ENT * 64;   // < N_REL*64
        SRsrc[(size_t)N_ENT * 64 + j] = xr[j];
    }
}

// ---------------------------------------------------------------- ent layer (fused, fp16 gather tables)
// 64 lanes per node; lane handles cols {2l, 2l+1}; head group = 8 lanes
__global__ __launch_bounds__(256) void k_ent_fused(
    const float* __restrict__ Pt,    // [N_ENT][128] fp32 (tail att + ba)
    const __half* __restrict__ PH,   // [N_ENT][256] fp16 (head att | head agg + bg)
    const float* __restrict__ SS,    // base+l*256, stride 512 fp32 (self att | self agg)
    const __half* __restrict__ RR,   // base+l*256, stride 512 fp16 (rel att | rel agg)
    const float* __restrict__ vec,   // 128
    const int2* __restrict__ hrE,
    const int* __restrict__ offs,
    float* __restrict__ upd)         // [N_ENT][128]
{
    int gid = blockIdx.x * 256 + threadIdx.x;
    int n = gid >> 6;
    int lane = threadIdx.x & 63;
    int c2 = lane << 1;
    float2 pt = *(const float2*)&Pt[(size_t)n * 128 + c2];
    float2 vc = *(const float2*)&vec[c2];
    const __half2* PHn = (const __half2*)(PH + (size_t)n * 256);
    float2 sa = __half22float2(PHn[lane]);
    float2 sg = __half22float2(PHn[64 + lane]);
    float2 ssA = *(const float2*)&SS[(size_t)n * 512 + c2];
    float2 ssG = *(const float2*)&SS[(size_t)n * 512 + 128 + c2];
    float vs = leaky(pt.x + sa.x + ssA.x) * vc.x + leaky(pt.y + sa.y + ssA.y) * vc.y;
#pragma unroll
    for (int o = 1; o < 8; o <<= 1) vs += __shfl_xor(vs, o, 64);
    float ws = __expf(vs);
    float s = ws;
    float accx = ws * (sg.x + ssG.x);
    float accy = ws * (sg.y + ssG.y);
    int e0 = offs[n], e1 = offs[n + 1];
    int i = e0;
    for (; i + 4 <= e1; i += 4) {
        int2 ev0 = hrE[i], ev1 = hrE[i + 1], ev2 = hrE[i + 2], ev3 = hrE[i + 3];
        const __half2* A0 = (const __half2*)(PH + (size_t)ev0.x * 256);
        const __half2* A1 = (const __half2*)(PH + (size_t)ev1.x * 256);
        const __half2* A2 = (const __half2*)(PH + (size_t)ev2.x * 256);
        const __half2* A3 = (const __half2*)(PH + (size_t)ev3.x * 256);
        const __half2* R0 = (const __half2*)(RR + (size_t)ev0.y * 512);
        const __half2* R1 = (const __half2*)(RR + (size_t)ev1.y * 512);
        const __half2* R2 = (const __half2*)(RR + (size_t)ev2.y * 512);
        const __half2* R3 = (const __half2*)(RR + (size_t)ev3.y * 512);
        __half2 a0h = A0[lane], g0h = A0[64 + lane];
        __half2 a1h = A1[lane], g1h = A1[64 + lane];
        __half2 a2h = A2[lane], g2h = A2[64 + lane];
        __half2 a3h = A3[lane], g3h = A3[64 + lane];
        __half2 r0h = R0[lane], q0h = R0[64 + lane];
        __half2 r1h = R1[lane], q1h = R1[64 + lane];
        __half2 r2h = R2[lane], q2h = R2[64 + lane];
        __half2 r3h = R3[lane], q3h = R3[64 + lane];
        float2 a0 = __half22float2(a0h), r0 = __half22float2(r0h);
        float2 a1 = __half22float2(a1h), r1 = __half22float2(r1h);
        float2 a2 = __half22float2(a2h), r2 = __half22float2(r2h);
        float2 a3 = __half22float2(a3h), r3 = __half22float2(r3h);
        float v0 = leaky(pt.x + a0.x + r0.x) * vc.x + leaky(pt.y + a0.y + r0.y) * vc.y;
        float v1 = leaky(pt.x + a1.x + r1.x) * vc.x + leaky(pt.y + a1.y + r1.y) * vc.y;
        float v2 = leaky(pt.x + a2.x + r2.x) * vc.x + leaky(pt.y + a2.y + r2.y) * vc.y;
        float v3 = leaky(pt.x + a3.x + r3.x) * vc.x + leaky(pt.y + a3.y + r3.y) * vc.y;
#pragma unroll
        for (int o = 1; o < 8; o <<= 1) {
            v0 += __shfl_xor(v0, o, 64); v1 += __shfl_xor(v1, o, 64);
            v2 += __shfl_xor(v2, o, 64); v3 += __shfl_xor(v3, o, 64);
        }
        float w0 = __expf(v0), w1 = __expf(v1), w2 = __expf(v2), w3 = __expf(v3);
        s += (w0 + w1) + (w2 + w3);
        float2 g0 = __half22float2(g0h), q0 = __half22float2(q0h);
        float2 g1 = __half22float2(g1h), q1 = __half22float2(q1h);
        float2 g2 = __half22float2(g2h), q2 = __half22float2(q2h);
        float2 g3 = __half22float2(g3h), q3 = __half22float2(q3h);
        accx = fmaf(w0, g0.x + q0.x, accx); accy = fmaf(w0, g0.y + q0.y, accy);
        accx = fmaf(w1, g1.x + q1.x, accx); accy = fmaf(w1, g1.y + q1.y, accy);
        accx = fmaf(w2, g2.x + q2.x, accx); accy = fmaf(w2, g2.y + q2.y, accy);
        accx = fmaf(w3, g3.x + q3.x, accx); accy = fmaf(w3, g3.y + q3.y, accy);
    }
    for (; i < e1; ++i) {
        int2 ev = hrE[i];
        const __half2* Ah = (const __half2*)(PH + (size_t)ev.x * 256);
        const __half2* Rh = (const __half2*)(RR + (size_t)ev.y * 512);
        float2 a = __half22float2(Ah[lane]), r = __half22float2(Rh[lane]);
        float2 g = __half22float2(Ah[64 + lane]), q = __half22float2(Rh[64 + lane]);
        float v = leaky(pt.x + a.x + r.x) * vc.x + leaky(pt.y + a.y + r.y) * vc.y;
#pragma unroll
        for (int o = 1; o < 8; o <<= 1) v += __shfl_xor(v, o, 64);
        float w = __expf(v);
        s += w;
        accx = fmaf(w, g.x + q.x, accx);
        accy = fmaf(w, g.y + q.y, accy);
    }
    float inv = 1.f / (s + EPSF);
    *(float2*)&upd[(size_t)n * 128 + c2] = make_float2(accx * inv, accy * inv);
}

// ---------------------------------------------------------------- launch
extern "C" void kernel_launch(void* const* d_in, const int* in_sizes, int n_in,
                              void* d_out, int out_size, void* d_ws, size_t ws_size,
                              hipStream_t stream) {
    const float* emb_ent      = (const float*)d_in[0];
    const float* emb_rel      = (const float*)d_in[1];
    const int*   tr           = (const int*)d_in[2];
    const int*   rt           = (const int*)d_in[3];
    const float* ent_proj1_W  = (const float*)d_in[4];
    const float* ent_proj1_b  = (const float*)d_in[5];
    const float* rel_proj1_W  = (const float*)d_in[6];
    const float* rel_proj1_b  = (const float*)d_in[7];
    const float* rel_attn_W   = (const float*)d_in[8];
    const float* rel_attn_b   = (const float*)d_in[9];
    const float* rel_attn_bin = (const float*)d_in[10];
    const float* rel_attn_vec = (const float*)d_in[11];
    const float* rel_aggr_W   = (const float*)d_in[12];
    const float* rel_aggr_b   = (const float*)d_in[13];
    const float* res_rel_W    = (const float*)d_in[14];
    const float* res_rel_b    = (const float*)d_in[15];
    const float* ent_attn_W   = (const float*)d_in[16];
    const float* ent_attn_b   = (const float*)d_in[17];
    const float* ent_attn_vec = (const float*)d_in[18];
    const float* ent_aggr_W   = (const float*)d_in[19];
    const float* ent_aggr_b   = (const float*)d_in[20];
    const float* res_ent_W    = (const float*)d_in[21];
    const float* res_ent_b    = (const float*)d_in[22];
    const float* ent_proj2_W  = (const float*)d_in[23];
    const float* ent_proj2_b  = (const float*)d_in[24];
    const float* rel_proj2_W  = (const float*)d_in[25];
    const float* rel_proj2_b  = (const float*)d_in[26];
    float* out = (float*)d_out;

    // workspace carve (256B aligned)
    size_t off = 0;
    char* base = (char*)d_ws;
    auto alloc = [&](size_t nbytes) -> void* {
        void* p = base + off;
        off += (nbytes + 255) & ~(size_t)255;
        return p;
    };
    float*  xe0    = (float*)alloc((size_t)N_ENT * 128 * 4);
    float*  xe1    = (float*)alloc((size_t)N_ENT * 128 * 4);
    float*  xr0    = (float*)alloc((size_t)N_REL * 64 * 4);
    float*  xr1    = (float*)alloc((size_t)N_REL * 64 * 4);
    float*  SRsrc  = (float*)alloc((size_t)(N_ENT + N_REL) * 64 * 4);
    float*  Pt     = (float*)alloc((size_t)N_ENT * 128 * 4);
    __half* PH     = (__half*)alloc((size_t)N_ENT * 256 * 2);
    float*  SSall  = (float*)alloc((size_t)N_ENT * 512 * 4);
    __half* RRall  = (__half*)alloc((size_t)N_REL * 512 * 2);
    float*  Arel   = (float*)alloc((size_t)N_REL * 192 * 4);
    float*  updE   = (float*)alloc((size_t)N_ENT * 128 * 4);
    float*  updR   = (float*)alloc((size_t)N_REL * 64 * 4);
    float*  Bp1    = (float*)alloc((size_t)2 * 384 * 128 * 4);
    float*  bias1  = (float*)alloc(2 * 384 * 4);
    float*  Bp2    = (float*)alloc(512 * 64 * 4);
    float*  Bp3    = (float*)alloc((size_t)2 * 192 * 64 * 4);
    float*  bias3  = (float*)alloc(2 * 192 * 4);
    int*  cnt   = (int*)alloc((size_t)(N_ENT + N_REL) * 4);
    int*  cntE  = cnt;
    int*  cntR  = cnt + N_ENT;
    int*  offsE = (int*)alloc((N_ENT + 1) * 4);
    int*  offsR = (int*)alloc((N_REL + 1) * 4);
    int*  curE  = (int*)alloc(N_ENT * 4);
    int*  curR  = (int*)alloc(N_REL * 4);
    int2* hrE   = (int2*)alloc((size_t)NE * 8);
    int2* tbR   = (int2*)alloc((size_t)NER * 8);

    auto gemm64 = [&](const float* A, const float* B, int ldb, const float* bias,
                      const float* add, float* C, int M, int N, int K, int relu) {
        dim3 g((N + 63) / 64, (M + 63) / 64);
        k_gemm<<<g, 256, 0, stream>>>(A, B, ldb, bias, add, C, M, N, K, relu);
    };
    auto gemm128 = [&](const float* A, const float* B, int ldb, const float* bias,
                       const float* add, float* C32, __half* C16, int split, int mode,
                       int M, int N, int K, int relu) {
        dim3 g((N + 127) / 128, (M + 127) / 128);
        k_gemm128x<<<g, 256, 0, stream>>>(A, B, ldb, bias, add, C32, C16, split, mode,
                                          M, N, K, relu);
    };

    // 1. pack all weights + zero counters
    k_pack_all<<<(2 * 384 * 128 + 255) / 256, 256, 0, stream>>>(
        ent_attn_W, ent_attn_b, ent_aggr_W, ent_aggr_b,
        rel_attn_W, rel_attn_b, rel_aggr_W, rel_aggr_b,
        Bp1, bias1, Bp2, Bp3, bias3, cnt);

    // 2-4. CSR builds
    k_count2<<<(NE + NER + 255) / 256, 256, 0, stream>>>(tr, rt, cntE, cntR);
    k_scan2<<<2, 1024, 0, stream>>>(cntE, offsE, curE, cntR, offsR, curR);
    k_scatter2<<<(NE + NER + 255) / 256, 256, 0, stream>>>(tr, rt, curE, curR, hrE, tbR);

    // 5-6. input projections
    gemm128(emb_ent, ent_proj1_W, 32, ent_proj1_b, nullptr, xe0, nullptr, 0, 2,
            N_ENT, 128, 32, 0);
    gemm64(emb_rel, rel_proj1_W, 16, rel_proj1_b, nullptr, xr0, N_REL, 64, 16, 0);

    // 7. relation layers
    for (int l = 0; l < 2; ++l) {
        const float* xin = l ? xr1 : xr0;
        float* xout = l ? xr0 : xr1;
        gemm64(xin, Bp3 + (size_t)l * 192 * 64, 64, bias3 + l * 192, nullptr, Arel,
               N_REL, 192, 64, 0);
        k_rel_fused<<<(N_REL * 64) / 256, 256, 0, stream>>>(
            Arel, rel_attn_vec + (size_t)l * 64, rel_attn_bin + (size_t)l * 80,
            tbR, offsR, updR);
        gemm64(xin, res_rel_W + (size_t)l * 64 * 64, 64, res_rel_b + (size_t)l * 64,
               updR, xout, N_REL, 64, 64, 1);
    }
    // final x_rel = xr0

    // 8. self_rel + append xr rows
    k_self_rel<<<(N_ENT * 64 + N_REL * 64) / 256, 256, 0, stream>>>(xr0, hrE, offsE, SRsrc);

    // 9. merged SS/RR GEMM for both layers (row-split mixed dtype)
    gemm128(SRsrc, Bp2, 64, nullptr, nullptr, SSall, RRall, N_ENT, 1,
            N_ENT + N_REL, 512, 64, 0);

    // 10. entity layers
    for (int l = 0; l < 2; ++l) {
        const float* xin = l ? xe1 : xe0;
        float* xout = l ? xe0 : xe1;
        gemm128(xin, Bp1 + (size_t)l * 384 * 128, 128, bias1 + l * 384, nullptr,
                Pt, PH, 128, 0, N_ENT, 384, 128, 0);
        k_ent_fused<<<(N_ENT * 64) / 256, 256, 0, stream>>>(
            Pt, PH, SSall + l * 256, RRall + l * 256,
            ent_attn_vec + (size_t)l * 128, hrE, offsE, updE);
        gemm128(xin, res_ent_W + (size_t)l * 128 * 128, 128, res_ent_b + (size_t)l * 128,
                updE, xout, nullptr, 0, 2, N_ENT, 128, 128, 1);
    }
    // final x_ent = xe0

    // 11. output projections
    gemm64(xe0, ent_proj2_W, 128, ent_proj2_b, nullptr, out, N_ENT, 32, 128, 0);
    gemm64(xr0, rel_proj2_W, 64, rel_proj2_b, nullptr, out + (size_t)N_ENT * 32,
           N_REL, 16, 64, 0);
}

// Round 4
// 306.312 us; speedup vs baseline: 4.1953x; 1.6101x over previous
//
#include <hip/hip_runtime.h>
#include <hip/hip_fp16.h>
#include <math.h>

constexpr int N_ENT = 20000;
constexpr int N_REL = 500;
constexpr int NE    = 300000;   // entity triplets
constexpr int NER   = 50000;    // relation triplets
constexpr int MPE   = 20096;    // 157*128 (padded entity rows)
constexpr int MPS   = 20608;    // 161*128 (padded self+rel rows)
constexpr float EPSF = 1e-16f;

__device__ __forceinline__ float leaky(float x) { return x > 0.f ? x : 0.2f * x; }

typedef __attribute__((ext_vector_type(8))) _Float16 f16x8;
typedef __attribute__((ext_vector_type(4))) float f32x4;

// ---------------------------------------------------------------- MFMA fp16 GEMM
// C[M,N] = A[M,K]fp16 @ B[N,K]fp16^T + bias.  BM=128, BN=64, BK=32, 4 waves.
// A rows must be readable up to m0+127 (padded allocs). B rows up to n0+63.
// Output: O16 (fp16, ld=ldo) or O32 (fp32, ld=ldo), masked to gm<M, gn<N.
__global__ __launch_bounds__(256) void k_hgemm(
    const _Float16* __restrict__ A,
    const _Float16* __restrict__ B,
    const float* __restrict__ bias,
    __half* __restrict__ O16, float* __restrict__ O32,
    int M, int N, int K, int ldo)
{
    __shared__ __align__(16) _Float16 lA[4 * 128 * 8];   // [kgrp][row][8]
    __shared__ __align__(16) _Float16 lB[4 * 64 * 8];    // [kgrp][row][8]
    int tid = threadIdx.x;
    int m0 = blockIdx.y * 128, n0 = blockIdx.x * 64;
    int l = tid & 63, w = tid >> 6;
    int wr = w >> 1, wc = w & 1;
    int kq = l >> 4, lr = l & 15;

    // staging: A has 512 16B slots (slot = kgrp*128+row), B has 256
    int sA0 = tid, sA1 = tid + 256;
    const uint4* pA0 = (const uint4*)(A + (size_t)(m0 + (sA0 & 127)) * K) + (sA0 >> 7);
    const uint4* pA1 = (const uint4*)(A + (size_t)(m0 + (sA1 & 127)) * K) + (sA1 >> 7);
    const uint4* pB  = (const uint4*)(B + (size_t)(n0 + (tid & 63)) * K) + (tid >> 6);

    f32x4 acc[4][2] = {};
    int nk = K >> 5;
    uint4 va0 = pA0[0], va1 = pA1[0], vb = pB[0];
    for (int t = 0; t < nk; ++t) {
        ((uint4*)lA)[sA0] = va0;
        ((uint4*)lA)[sA1] = va1;
        ((uint4*)lB)[tid] = vb;
        __syncthreads();
        if (t + 1 < nk) {
            va0 = pA0[(t + 1) * 4];
            va1 = pA1[(t + 1) * 4];
            vb  = pB[(t + 1) * 4];
        }
        f16x8 bf0 = *(const f16x8*)&lB[(kq * 64 + wc * 32 + lr) * 8];
        f16x8 bf1 = *(const f16x8*)&lB[(kq * 64 + wc * 32 + 16 + lr) * 8];
#pragma unroll
        for (int fm = 0; fm < 4; ++fm) {
            f16x8 af = *(const f16x8*)&lA[(kq * 128 + wr * 64 + fm * 16 + lr) * 8];
            acc[fm][0] = __builtin_amdgcn_mfma_f32_16x16x32_f16(af, bf0, acc[fm][0], 0, 0, 0);
            acc[fm][1] = __builtin_amdgcn_mfma_f32_16x16x32_f16(af, bf1, acc[fm][1], 0, 0, 0);
        }
        __syncthreads();
    }
    // epilogue
    int gn0 = n0 + wc * 32 + lr;
    int gn1 = gn0 + 16;
    float bc0 = (bias && gn0 < N) ? bias[gn0] : 0.f;
    float bc1 = (bias && gn1 < N) ? bias[gn1] : 0.f;
#pragma unroll
    for (int fm = 0; fm < 4; ++fm) {
#pragma unroll
        for (int j = 0; j < 4; ++j) {
            int gm = m0 + wr * 64 + fm * 16 + kq * 4 + j;
            if (gm >= M) continue;
            float v0 = acc[fm][0][j] + bc0;
            float v1 = acc[fm][1][j] + bc1;
            if (O16) {
                if (gn0 < N) O16[(size_t)gm * ldo + gn0] = __float2half_rn(v0);
                if (gn1 < N) O16[(size_t)gm * ldo + gn1] = __float2half_rn(v1);
            } else {
                if (gn0 < N) O32[(size_t)gm * ldo + gn0] = v0;
                if (gn1 < N) O32[(size_t)gm * ldo + gn1] = v1;
            }
        }
    }
}

// ---------------------------------------------------------------- GEMM 64x64 fp32 (rel-side, tiny)
__global__ __launch_bounds__(256) void k_gemm(
    const float* __restrict__ A,
    const float* __restrict__ B, int ldb,
    const float* __restrict__ bias,
    float* __restrict__ C,
    int M, int N, int K)
{
    __shared__ float As[32][65];
    __shared__ float Bs[32][65];
    int tid = threadIdx.x;
    int m0 = blockIdx.y * 64, n0 = blockIdx.x * 64;
    int tx = tid & 15, ty = tid >> 4;
    float acc[4][4] = {};
    for (int k0 = 0; k0 < K; k0 += 32) {
#pragma unroll
        for (int t = 0; t < 8; ++t) {
            int idx = t * 256 + tid;
            int m = idx >> 5, k = idx & 31;
            int gk = k0 + k;
            int gm = m0 + m;
            As[k][m] = (gm < M && gk < K) ? A[(size_t)gm * K + gk] : 0.f;
            int gn = n0 + m;
            Bs[k][m] = (gn < N && gk < K) ? B[(size_t)gn * ldb + gk] : 0.f;
        }
        __syncthreads();
#pragma unroll
        for (int k = 0; k < 32; ++k) {
            float a[4], b[4];
#pragma unroll
            for (int i = 0; i < 4; ++i) a[i] = As[k][ty * 4 + i];
#pragma unroll
            for (int j = 0; j < 4; ++j) b[j] = Bs[k][tx * 4 + j];
#pragma unroll
            for (int i = 0; i < 4; ++i)
#pragma unroll
                for (int j = 0; j < 4; ++j)
                    acc[i][j] = fmaf(a[i], b[j], acc[i][j]);
        }
        __syncthreads();
    }
#pragma unroll
    for (int i = 0; i < 4; ++i) {
        int gm = m0 + ty * 4 + i;
        if (gm >= M) continue;
#pragma unroll
        for (int j = 0; j < 4; ++j) {
            int gn = n0 + tx * 4 + j;
            if (gn >= N) continue;
            float v = acc[i][j];
            if (bias) v += bias[gn];
            C[(size_t)gm * N + gn] = v;
        }
    }
}

// ---------------------------------------------------------------- mega-pack + fp16 converts + zero counters
__global__ void k_pack_all(
    const float* __restrict__ emb_ent,
    const float* __restrict__ Wa_e, const float* __restrict__ ba_e,
    const float* __restrict__ Wg_e, const float* __restrict__ bg_e,
    const float* __restrict__ Wres_e, const float* __restrict__ bres_e,
    const float* __restrict__ Wa_r, const float* __restrict__ ba_r,
    const float* __restrict__ Wg_r, const float* __restrict__ bg_r,
    const float* __restrict__ Wres_r, const float* __restrict__ bres_r,
    const float* __restrict__ Wp1e, const float* __restrict__ Wp2e,
    _Float16* __restrict__ embh,
    _Float16* __restrict__ Bp1f, float* __restrict__ bias1,
    _Float16* __restrict__ Bp2f,
    float* __restrict__ Bp3, float* __restrict__ bias3,
    _Float16* __restrict__ Bpe1, _Float16* __restrict__ Bpe2,
    int* __restrict__ cnt)
{
    int gid = blockIdx.x * 256 + threadIdx.x;
    if (gid < N_ENT * 32) embh[gid] = (_Float16)emb_ent[gid];
    if (gid < 2 * 512 * 128) {          // Bp1f[l][512][128]: Wa[:, :128] | Wa[:,128:256] | Wg[:, :128] | Wres
        int l = gid / (512 * 128), rem = gid % (512 * 128);
        int row = rem >> 7, k = rem & 127;
        const float* Wa = Wa_e + (size_t)l * 128 * 320;
        const float* Wg = Wg_e + (size_t)l * 128 * 192;
        const float* Wr = Wres_e + (size_t)l * 128 * 128;
        float v;
        if (row < 128) v = Wa[row * 320 + k];
        else if (row < 256) v = Wa[(row - 128) * 320 + 128 + k];
        else if (row < 384) v = Wg[(row - 256) * 192 + k];
        else v = Wr[(row - 384) * 128 + k];
        Bp1f[gid] = (_Float16)v;
    }
    if (gid < 512 * 64) {               // Bp2f[l*256 + (att|agg)][64]
        int row = gid >> 6, k = gid & 63;
        int l = row >> 8, r2 = row & 255;
        const float* Wa = Wa_e + (size_t)l * 128 * 320;
        const float* Wg = Wg_e + (size_t)l * 128 * 192;
        float v = (r2 < 128) ? Wa[r2 * 320 + 256 + k] : Wg[(r2 - 128) * 192 + 128 + k];
        Bp2f[gid] = (_Float16)v;
    }
    if (gid < 2 * 256 * 64) {           // Bp3[l][256][64] fp32: Wa(2 slabs) | Wg | Wres
        int l = gid / (256 * 64), rem = gid % (256 * 64);
        int row = rem >> 6, k = rem & 63;
        const float* Wa = Wa_r + (size_t)l * 64 * 128;
        const float* Wg = Wg_r + (size_t)l * 64 * 64;
        const float* Wr = Wres_r + (size_t)l * 64 * 64;
        float v;
        if (row < 64) v = Wa[row * 128 + k];
        else if (row < 128) v = Wa[(row - 64) * 128 + 64 + k];
        else if (row < 192) v = Wg[(row - 128) * 64 + k];
        else v = Wr[(row - 192) * 64 + k];
        Bp3[gid] = v;
    }
    if (gid < 128 * 32) Bpe1[gid] = (_Float16)Wp1e[gid];
    if (gid < 64 * 128) {               // Bpe2 zero-padded to 64 rows
        int row = gid >> 7, k = gid & 127;
        Bpe2[gid] = (row < 32) ? (_Float16)Wp2e[row * 128 + k] : (_Float16)0.f;
    }
    if (gid < 2 * 512) {
        int l = gid / 512, j = gid % 512;
        float v;
        if (j < 128) v = ba_e[l * 128 + j];
        else if (j < 256) v = 0.f;
        else if (j < 384) v = bg_e[l * 128 + j - 256];
        else v = bres_e[l * 128 + j - 384];
        bias1[gid] = v;
    }
    if (gid < 2 * 256) {
        int l = gid / 256, j = gid % 256;
        float v;
        if (j < 64) v = ba_r[l * 64 + j];
        else if (j < 128) v = 0.f;
        else if (j < 192) v = bg_r[l * 64 + j - 128];
        else v = bres_r[l * 64 + j - 192];
        bias3[gid] = v;
    }
    if (gid < N_ENT + N_REL) cnt[gid] = 0;
}

// ---------------------------------------------------------------- CSR build
__global__ void k_count2(const int* __restrict__ tr, const int* __restrict__ rt,
                         int* __restrict__ cntE, int* __restrict__ cntR) {
    int i = blockIdx.x * 256 + threadIdx.x;
    if (i < NE) atomicAdd(&cntE[tr[i * 3 + 2]], 1);
    else if (i < NE + NER) atomicAdd(&cntR[rt[(i - NE) * 3 + 0]], 1);
}

__global__ __launch_bounds__(1024) void k_scan2(
    const int* __restrict__ cntE, int* __restrict__ offsE, int* __restrict__ curE,
    const int* __restrict__ cntR, int* __restrict__ offsR, int* __restrict__ curR)
{
    const int* cnt = blockIdx.x ? cntR : cntE;
    int* offs = blockIdx.x ? offsR : offsE;
    int* cur  = blockIdx.x ? curR : curE;
    int n = blockIdx.x ? N_REL : N_ENT;
    __shared__ int wsum[16];
    __shared__ int sbase;
    int lane = threadIdx.x & 63, wid = threadIdx.x >> 6;
    if (threadIdx.x == 0) sbase = 0;
    __syncthreads();
    for (int start = 0; start < n; start += 1024) {
        int i = start + threadIdx.x;
        int v = (i < n) ? cnt[i] : 0;
        int x = v;
#pragma unroll
        for (int o = 1; o < 64; o <<= 1) {
            int y = __shfl_up(x, o, 64);
            if (lane >= o) x += y;
        }
        if (lane == 63) wsum[wid] = x;
        __syncthreads();
        if (wid == 0 && lane < 16) {
            int wv = wsum[lane];
#pragma unroll
            for (int o = 1; o < 16; o <<= 1) {
                int y = __shfl_up(wv, o, 64);
                if (lane >= o) wv += y;
            }
            wsum[lane] = wv;
        }
        __syncthreads();
        int excl = sbase + (wid ? wsum[wid - 1] : 0) + x - v;
        if (i < n) { offs[i] = excl; cur[i] = excl; }
        __syncthreads();
        if (threadIdx.x == 0) sbase += wsum[15];
        __syncthreads();
    }
    if (threadIdx.x == 0) offs[n] = sbase;
}

__global__ void k_scatter2(const int* __restrict__ tr, const int* __restrict__ rt,
                           int* __restrict__ curE, int* __restrict__ curR,
                           int2* __restrict__ hrE, int2* __restrict__ tbR) {
    int i = blockIdx.x * 256 + threadIdx.x;
    if (i < NE) {
        int pos = atomicAdd(&curE[tr[i * 3 + 2]], 1);
        hrE[pos] = make_int2(tr[i * 3 + 0], tr[i * 3 + 1]);
    } else if (i < NE + NER) {
        int e = i - NE;
        int pos = atomicAdd(&curR[rt[e * 3 + 0]], 1);
        tbR[pos] = make_int2(rt[e * 3 + 1], rt[e * 3 + 2]);
    }
}

// ---------------------------------------------------------------- rel layer (fused attn+agg+residual+relu)
__global__ __launch_bounds__(256) void k_rel_fused(
    const float* __restrict__ AR,     // 500x256: Ah+ba | At | G+bg | R(res)
    const float* __restrict__ vec,    // 64
    const float* __restrict__ abin,   // 10x8
    const int2* __restrict__ tbR,
    const int* __restrict__ offs,
    float* __restrict__ xout)         // 500x64
{
    int gid = blockIdx.x * 256 + threadIdx.x;
    int n = gid >> 6, col = gid & 63;
    int head = col >> 3;
    float ah = AR[n * 256 + col];
    float vc = vec[col];
    int e0 = offs[n], e1 = offs[n + 1];
    float s = 0.f, acc = 0.f;
    int i = e0;
    for (; i + 4 <= e1; i += 4) {
        int2 t0 = tbR[i], t1 = tbR[i + 1], t2 = tbR[i + 2], t3 = tbR[i + 3];
        float v0 = leaky(ah + AR[t0.x * 256 + 64 + col]) * vc;
        float v1 = leaky(ah + AR[t1.x * 256 + 64 + col]) * vc;
        float v2 = leaky(ah + AR[t2.x * 256 + 64 + col]) * vc;
        float v3 = leaky(ah + AR[t3.x * 256 + 64 + col]) * vc;
        float g0 = AR[t0.x * 256 + 128 + col];
        float g1 = AR[t1.x * 256 + 128 + col];
        float g2 = AR[t2.x * 256 + 128 + col];
        float g3 = AR[t3.x * 256 + 128 + col];
#pragma unroll
        for (int o = 1; o < 8; o <<= 1) {
            v0 += __shfl_xor(v0, o, 64); v1 += __shfl_xor(v1, o, 64);
            v2 += __shfl_xor(v2, o, 64); v3 += __shfl_xor(v3, o, 64);
        }
        float w0 = __expf(v0 + abin[t0.y * 8 + head]);
        float w1 = __expf(v1 + abin[t1.y * 8 + head]);
        float w2 = __expf(v2 + abin[t2.y * 8 + head]);
        float w3 = __expf(v3 + abin[t3.y * 8 + head]);
        s += (w0 + w1) + (w2 + w3);
        acc = fmaf(w0, g0, acc); acc = fmaf(w1, g1, acc);
        acc = fmaf(w2, g2, acc); acc = fmaf(w3, g3, acc);
    }
    for (; i < e1; ++i) {
        int2 tb = tbR[i];
        float v = leaky(ah + AR[tb.x * 256 + 64 + col]) * vc;
        float g = AR[tb.x * 256 + 128 + col];
#pragma unroll
        for (int o = 1; o < 8; o <<= 1) v += __shfl_xor(v, o, 64);
        float w = __expf(v + abin[tb.y * 8 + head]);
        s += w;
        acc = fmaf(w, g, acc);
    }
    float upd = acc / (s + EPSF);
    xout[n * 64 + col] = fmaxf(AR[n * 256 + 192 + col] + upd, 0.f);
}

// ---------------------------------------------------------------- self_rel -> SRsrc fp16 (+ xr tail)
__global__ __launch_bounds__(256) void k_self_rel(
    const float* __restrict__ xr, const int2* __restrict__ hrE,
    const int* __restrict__ offs, __half* __restrict__ SRsrc)
{
    int gid = blockIdx.x * 256 + threadIdx.x;
    if (gid < N_ENT * 64) {
        int n = gid >> 6, col = gid & 63;
        int e0 = offs[n], e1 = offs[n + 1];
        float acc = 0.f;
        int i = e0;
        for (; i + 4 <= e1; i += 4) {
            int r0 = hrE[i].y, r1 = hrE[i + 1].y, r2 = hrE[i + 2].y, r3 = hrE[i + 3].y;
            acc += xr[r0 * 64 + col] + xr[r1 * 64 + col] + xr[r2 * 64 + col] + xr[r3 * 64 + col];
        }
        for (; i < e1; ++i) acc += xr[hrE[i].y * 64 + col];
        SRsrc[(size_t)n * 64 + col] = __float2half_rn(acc / ((float)(e1 - e0) + EPSF));
    } else {
        int j = gid - N_ENT * 64;   // < N_REL*64
        SRsrc[(size_t)N_ENT * 64 + j] = __float2half_rn(xr[j]);
    }
}

// ---------------------------------------------------------------- ent layer (fused attn+agg+residual+relu)
// E16 row [512]: pt+ba (128) | head att (128) | head agg+bg (128) | R=x@Wres+b (128)
// Fl  row [512], pass base pre-offset by l*256: self/rel att (128) | agg (128)
__global__ __launch_bounds__(256) void k_ent_fused(
    const __half* __restrict__ E16,
    const __half* __restrict__ Fl,
    const float* __restrict__ vec,    // 128
    const int2* __restrict__ hrE,
    const int* __restrict__ offs,
    __half* __restrict__ xout)        // [MPE][128] fp16
{
    int gid = blockIdx.x * 256 + threadIdx.x;
    int n = gid >> 6;
    int l = threadIdx.x & 63;
    int c2 = l << 1;
    const __half2* En = (const __half2*)(E16 + (size_t)n * 512);
    const __half2* Fn = (const __half2*)(Fl + (size_t)n * 512);
    float2 pt = __half22float2(En[l]);
    float2 vc = *(const float2*)&vec[c2];
    float2 sa = __half22float2(En[64 + l]);
    float2 sg = __half22float2(En[128 + l]);
    float2 rr = __half22float2(En[192 + l]);
    float2 ssA = __half22float2(Fn[l]);
    float2 ssG = __half22float2(Fn[64 + l]);
    float vs = leaky(pt.x + sa.x + ssA.x) * vc.x + leaky(pt.y + sa.y + ssA.y) * vc.y;
#pragma unroll
    for (int o = 1; o < 8; o <<= 1) vs += __shfl_xor(vs, o, 64);
    float ws = __expf(vs);
    float s = ws;
    float accx = ws * (sg.x + ssG.x);
    float accy = ws * (sg.y + ssG.y);
    int e0 = offs[n], e1 = offs[n + 1];
    int i = e0;
    for (; i + 4 <= e1; i += 4) {
        int2 ev0 = hrE[i], ev1 = hrE[i + 1], ev2 = hrE[i + 2], ev3 = hrE[i + 3];
        const __half2* A0 = (const __half2*)(E16 + (size_t)ev0.x * 512 + 128);
        const __half2* A1 = (const __half2*)(E16 + (size_t)ev1.x * 512 + 128);
        const __half2* A2 = (const __half2*)(E16 + (size_t)ev2.x * 512 + 128);
        const __half2* A3 = (const __half2*)(E16 + (size_t)ev3.x * 512 + 128);
        const __half2* R0 = (const __half2*)(Fl + (size_t)(N_ENT + ev0.y) * 512);
        const __half2* R1 = (const __half2*)(Fl + (size_t)(N_ENT + ev1.y) * 512);
        const __half2* R2 = (const __half2*)(Fl + (size_t)(N_ENT + ev2.y) * 512);
        const __half2* R3 = (const __half2*)(Fl + (size_t)(N_ENT + ev3.y) * 512);
        __half2 a0h = A0[l], g0h = A0[64 + l], r0h = R0[l], q0h = R0[64 + l];
        __half2 a1h = A1[l], g1h = A1[64 + l], r1h = R1[l], q1h = R1[64 + l];
        __half2 a2h = A2[l], g2h = A2[64 + l], r2h = R2[l], q2h = R2[64 + l];
        __half2 a3h = A3[l], g3h = A3[64 + l], r3h = R3[l], q3h = R3[64 + l];
        float2 a0 = __half22float2(a0h), r0 = __half22float2(r0h);
        float2 a1 = __half22float2(a1h), r1 = __half22float2(r1h);
        float2 a2 = __half22float2(a2h), r2 = __half22float2(r2h);
        float2 a3 = __half22float2(a3h), r3 = __half22float2(r3h);
        float v0 = leaky(pt.x + a0.x + r0.x) * vc.x + leaky(pt.y + a0.y + r0.y) * vc.y;
        float v1 = leaky(pt.x + a1.x + r1.x) * vc.x + leaky(pt.y + a1.y + r1.y) * vc.y;
        float v2 = leaky(pt.x + a2.x + r2.x) * vc.x + leaky(pt.y + a2.y + r2.y) * vc.y;
        float v3 = leaky(pt.x + a3.x + r3.x) * vc.x + leaky(pt.y + a3.y + r3.y) * vc.y;
#pragma unroll
        for (int o = 1; o < 8; o <<= 1) {
            v0 += __shfl_xor(v0, o, 64); v1 += __shfl_xor(v1, o, 64);
            v2 += __shfl_xor(v2, o, 64); v3 += __shfl_xor(v3, o, 64);
        }
        float w0 = __expf(v0), w1 = __expf(v1), w2 = __expf(v2), w3 = __expf(v3);
        s += (w0 + w1) + (w2 + w3);
        float2 g0 = __half22float2(g0h), q0 = __half22float2(q0h);
        float2 g1 = __half22float2(g1h), q1 = __half22float2(q1h);
        float2 g2 = __half22float2(g2h), q2 = __half22float2(q2h);
        float2 g3 = __half22float2(g3h), q3 = __half22float2(q3h);
        accx = fmaf(w0, g0.x + q0.x, accx); accy = fmaf(w0, g0.y + q0.y, accy);
        accx = fmaf(w1, g1.x + q1.x, accx); accy = fmaf(w1, g1.y + q1.y, accy);
        accx = fmaf(w2, g2.x + q2.x, accx); accy = fmaf(w2, g2.y + q2.y, accy);
        accx = fmaf(w3, g3.x + q3.x, accx); accy = fmaf(w3, g3.y + q3.y, accy);
    }
    for (; i < e1; ++i) {
        int2 ev = hrE[i];
        const __half2* Ah = (const __half2*)(E16 + (size_t)ev.x * 512 + 128);
        const __half2* Rh = (const __half2*)(Fl + (size_t)(N_ENT + ev.y) * 512);
        float2 a = __half22float2(Ah[l]), r = __half22float2(Rh[l]);
        float2 g = __half22float2(Ah[64 + l]), q = __half22float2(Rh[64 + l]);
        float v = leaky(pt.x + a.x + r.x) * vc.x + leaky(pt.y + a.y + r.y) * vc.y;
#pragma unroll
        for (int o = 1; o < 8; o <<= 1) v += __shfl_xor(v, o, 64);
        float w = __expf(v);
        s += w;
        accx = fmaf(w, g.x + q.x, accx);
        accy = fmaf(w, g.y + q.y, accy);
    }
    float inv = 1.f / (s + EPSF);
    float ox = fmaxf(rr.x + accx * inv, 0.f);
    float oy = fmaxf(rr.y + accy * inv, 0.f);
    ((__half2*)(xout + (size_t)n * 128))[l] = __floats2half2_rn(ox, oy);
}

// ---------------------------------------------------------------- launch
extern "C" void kernel_launch(void* const* d_in, const int* in_sizes, int n_in,
                              void* d_out, int out_size, void* d_ws, size_t ws_size,
                              hipStream_t stream) {
    const float* emb_ent      = (const float*)d_in[0];
    const float* emb_rel      = (const float*)d_in[1];
    const int*   tr           = (const int*)d_in[2];
    const int*   rt           = (const int*)d_in[3];
    const float* ent_proj1_W  = (const float*)d_in[4];
    const float* ent_proj1_b  = (const float*)d_in[5];
    const float* rel_proj1_W  = (const float*)d_in[6];
    const float* rel_proj1_b  = (const float*)d_in[7];
    const float* rel_attn_W   = (const float*)d_in[8];
    const float* rel_attn_b   = (const float*)d_in[9];
    const float* rel_attn_bin = (const float*)d_in[10];
    const float* rel_attn_vec = (const float*)d_in[11];
    const float* rel_aggr_W   = (const float*)d_in[12];
    const float* rel_aggr_b   = (const float*)d_in[13];
    const float* res_rel_W    = (const float*)d_in[14];
    const float* res_rel_b    = (const float*)d_in[15];
    const float* ent_attn_W   = (const float*)d_in[16];
    const float* ent_attn_b   = (const float*)d_in[17];
    const float* ent_attn_vec = (const float*)d_in[18];
    const float* ent_aggr_W   = (const float*)d_in[19];
    const float* ent_aggr_b   = (const float*)d_in[20];
    const float* res_ent_W    = (const float*)d_in[21];
    const float* res_ent_b    = (const float*)d_in[22];
    const float* ent_proj2_W  = (const float*)d_in[23];
    const float* ent_proj2_b  = (const float*)d_in[24];
    const float* rel_proj2_W  = (const float*)d_in[25];
    const float* rel_proj2_b  = (const float*)d_in[26];
    float* out = (float*)d_out;

    // workspace carve (256B aligned)
    size_t off = 0;
    char* base = (char*)d_ws;
    auto alloc = [&](size_t nbytes) -> void* {
        void* p = base + off;
        off += (nbytes + 255) & ~(size_t)255;
        return p;
    };
    _Float16* embh  = (_Float16*)alloc((size_t)MPE * 32 * 2);
    __half*   xea   = (__half*)alloc((size_t)MPE * 128 * 2);
    __half*   xeb   = (__half*)alloc((size_t)MPE * 128 * 2);
    __half*   E16   = (__half*)alloc((size_t)MPE * 512 * 2);
    __half*   F16   = (__half*)alloc((size_t)MPS * 512 * 2);
    __half*   SRsrc = (__half*)alloc((size_t)MPS * 64 * 2);
    float*    xr0   = (float*)alloc((size_t)N_REL * 64 * 4);
    float*    xr1   = (float*)alloc((size_t)N_REL * 64 * 4);
    float*    AR    = (float*)alloc((size_t)N_REL * 256 * 4);
    _Float16* Bp1f  = (_Float16*)alloc((size_t)2 * 512 * 128 * 2);
    float*    bias1 = (float*)alloc(2 * 512 * 4);
    _Float16* Bp2f  = (_Float16*)alloc(512 * 64 * 2);
    float*    Bp3   = (float*)alloc((size_t)2 * 256 * 64 * 4);
    float*    bias3 = (float*)alloc(2 * 256 * 4);
    _Float16* Bpe1  = (_Float16*)alloc(128 * 32 * 2);
    _Float16* Bpe2  = (_Float16*)alloc(64 * 128 * 2);
    int*  cnt   = (int*)alloc((size_t)(N_ENT + N_REL) * 4);
    int*  cntE  = cnt;
    int*  cntR  = cnt + N_ENT;
    int*  offsE = (int*)alloc((N_ENT + 1) * 4);
    int*  offsR = (int*)alloc((N_REL + 1) * 4);
    int*  curE  = (int*)alloc(N_ENT * 4);
    int*  curR  = (int*)alloc(N_REL * 4);
    int2* hrE   = (int2*)alloc((size_t)NE * 8);
    int2* tbR   = (int2*)alloc((size_t)NER * 8);

    auto gemm64 = [&](const float* A, const float* B, int ldb, const float* bias,
                      float* C, int M, int N, int K) {
        dim3 g((N + 63) / 64, (M + 63) / 64);
        k_gemm<<<g, 256, 0, stream>>>(A, B, ldb, bias, C, M, N, K);
    };
    auto hgemm = [&](const _Float16* A, const _Float16* B, const float* bias,
                     __half* O16, float* O32, int M, int N, int K, int ldo, int gridN) {
        dim3 g(gridN, (M + 127) / 128);
        k_hgemm<<<g, 256, 0, stream>>>(A, B, bias, O16, O32, M, N, K, ldo);
    };

    // 1. pack all weights, convert emb_ent to fp16, zero counters
    k_pack_all<<<(N_ENT * 32 + 255) / 256, 256, 0, stream>>>(
        emb_ent,
        ent_attn_W, ent_attn_b, ent_aggr_W, ent_aggr_b, res_ent_W, res_ent_b,
        rel_attn_W, rel_attn_b, rel_aggr_W, rel_aggr_b, res_rel_W, res_rel_b,
        ent_proj1_W, ent_proj2_W,
        embh, Bp1f, bias1, Bp2f, Bp3, bias3, Bpe1, Bpe2, cnt);

    // 2-4. CSR builds
    k_count2<<<(NE + NER + 255) / 256, 256, 0, stream>>>(tr, rt, cntE, cntR);
    k_scan2<<<2, 1024, 0, stream>>>(cntE, offsE, curE, cntR, offsR, curR);
    k_scatter2<<<(NE + NER + 255) / 256, 256, 0, stream>>>(tr, rt, curE, curR, hrE, tbR);

    // 5-6. input projections
    hgemm(embh, Bpe1, ent_proj1_b, xea, nullptr, N_ENT, 128, 32, 128, 2);
    gemm64(emb_rel, rel_proj1_W, 16, rel_proj1_b, xr0, N_REL, 64, 16);

    // 7. relation layers (GEMM: Arel|res merged N=256; fused does +res+relu)
    for (int l = 0; l < 2; ++l) {
        const float* xin = l ? xr1 : xr0;
        float* xout = l ? xr0 : xr1;
        gemm64(xin, Bp3 + (size_t)l * 256 * 64, 64, bias3 + l * 256, AR, N_REL, 256, 64);
        k_rel_fused<<<(N_REL * 64) / 256, 256, 0, stream>>>(
            AR, rel_attn_vec + (size_t)l * 64, rel_attn_bin + (size_t)l * 80,
            tbR, offsR, xout);
    }
    // final x_rel = xr0

    // 8. self_rel -> SRsrc fp16 (+ xr tail rows)
    k_self_rel<<<((N_ENT + N_REL) * 64) / 256, 256, 0, stream>>>(xr0, hrE, offsE, SRsrc);

    // 9. merged SS/RR GEMM for both layers -> F16 fp16
    hgemm((const _Float16*)SRsrc, Bp2f, nullptr, F16, nullptr, N_ENT + N_REL, 512, 64, 512, 8);

    // 10. entity layers (GEMM: Pt|PHatt|PHagg|R merged N=512; fused does +res+relu)
    for (int l = 0; l < 2; ++l) {
        const __half* xin = l ? xeb : xea;
        __half* xout = l ? xea : xeb;
        hgemm((const _Float16*)xin, Bp1f + (size_t)l * 512 * 128, bias1 + l * 512,
              E16, nullptr, N_ENT, 512, 128, 512, 8);
        k_ent_fused<<<(N_ENT * 64) / 256, 256, 0, stream>>>(
            E16, F16 + (size_t)l * 256, ent_attn_vec + (size_t)l * 128,
            hrE, offsE, xout);
    }
    const __half* xfin = xea;  // after l=1, output went to xea

    // 11. output projections
    hgemm((const _Float16*)xfin, Bpe2, ent_proj2_b, nullptr, out, N_ENT, 32, 128, 32, 1);
    gemm64(xr0, rel_proj2_W, 64, rel_proj2_b, out + (size_t)N_ENT * 32, N_REL, 16, 64);
}